// Round 21
// baseline (2170.687 us; speedup 1.0000x reference)
//
#include <hip/hip_runtime.h>
#include <hip/hip_bf16.h>

typedef __hip_bfloat16 bf16;
typedef unsigned short u16;

#define R_RECON 3145728
#define N_IDX   65536

__device__ __forceinline__ float ldg_in(const void* p, int i, int fl) {
  return fl ? ((const float*)p)[i] : __bfloat162float(((const bf16*)p)[i]);
}
__device__ __forceinline__ float cvt(float v) { return v; }
__device__ __forceinline__ float cvt(bf16 v) { return __bfloat162float(v); }

__global__ __launch_bounds__(256) void k_detect(const u16* __restrict__ p, int* __restrict__ flag) {
  __shared__ int s;
  if (threadIdx.x == 0) s = 0;
  __syncthreads();
  for (int i = threadIdx.x; i < 4096; i += 256) {
    float f = __uint_as_float(((unsigned)p[i]) << 16);
    if (!(fabsf(f) < 16384.f)) atomicOr(&s, 1);
  }
  __syncthreads();
  if (threadIdx.x == 0) flag[0] = s;
}

// ---------------- enc1: s2 k4 p1, 3ch 128x128 -> 64ch 64x64; 2 co/thread, 4-wide ox ----
template<typename T>
__device__ __forceinline__ void enc1_loop(
    const T* __restrict__ ip, int iy0, int cx0, const float* sW,
    float& a0, float& a1, float& a2, float& a3,
    float& b0, float& b1, float& b2, float& b3)
{
  #pragma unroll
  for (int ci = 0; ci < 3; ++ci) {
    const T* cp = ip + ci * 16384;
    #pragma unroll
    for (int ky = 0; ky < 4; ++ky) {
      int iy = iy0 + ky;
      if ((unsigned)iy < 128u) {
        const T* rp = cp + iy * 128;
        float x0 = (cx0 >= 0) ? cvt(rp[cx0]) : 0.f;
        float x1 = cvt(rp[cx0 + 1]), x2 = cvt(rp[cx0 + 2]);
        float x3 = cvt(rp[cx0 + 3]), x4 = cvt(rp[cx0 + 4]);
        float x5 = cvt(rp[cx0 + 5]), x6 = cvt(rp[cx0 + 6]);
        float x7 = cvt(rp[cx0 + 7]), x8 = cvt(rp[cx0 + 8]);
        float x9 = (cx0 + 9 < 128) ? cvt(rp[cx0 + 9]) : 0.f;
        const float* WA = sW + ci * 16 + ky * 4;
        float wa0 = WA[0], wa1 = WA[1], wa2 = WA[2], wa3 = WA[3];
        a0 = fmaf(x0, wa0, fmaf(x1, wa1, fmaf(x2, wa2, fmaf(x3, wa3, a0))));
        a1 = fmaf(x2, wa0, fmaf(x3, wa1, fmaf(x4, wa2, fmaf(x5, wa3, a1))));
        a2 = fmaf(x4, wa0, fmaf(x5, wa1, fmaf(x6, wa2, fmaf(x7, wa3, a2))));
        a3 = fmaf(x6, wa0, fmaf(x7, wa1, fmaf(x8, wa2, fmaf(x9, wa3, a3))));
        const float* WB = WA + 48;
        float wb0 = WB[0], wb1 = WB[1], wb2 = WB[2], wb3 = WB[3];
        b0 = fmaf(x0, wb0, fmaf(x1, wb1, fmaf(x2, wb2, fmaf(x3, wb3, b0))));
        b1 = fmaf(x2, wb0, fmaf(x3, wb1, fmaf(x4, wb2, fmaf(x5, wb3, b1))));
        b2 = fmaf(x4, wb0, fmaf(x5, wb1, fmaf(x6, wb2, fmaf(x7, wb3, b2))));
        b3 = fmaf(x6, wb0, fmaf(x7, wb1, fmaf(x8, wb2, fmaf(x9, wb3, b3))));
      }
    }
  }
}

__global__ __launch_bounds__(256) void k_enc1(
    const void* __restrict__ patch, const void* __restrict__ w,
    const void* __restrict__ bias, float* __restrict__ out,
    const int* __restrict__ flag, int n0)
{
  __shared__ float sW[96];
  __shared__ float sB[2];
  int fl = flag[0];
  int bid = blockIdx.x;
  int rg = bid & 3; int t = bid >> 2;
  int cp = t & 31;  int n = t >> 5;
  int co0 = cp * 2;
  int tid = threadIdx.x;
  if (tid < 96) sW[tid] = ldg_in(w, co0 * 48 + tid, fl);
  if (tid < 2)  sB[tid] = ldg_in(bias, co0 + tid, fl);
  __syncthreads();
  int ty = tid >> 4, txq = tid & 15;
  int oy = rg * 16 + ty;
  int ox0 = txq * 4;
  int iy0 = 2 * oy - 1, cx0 = 2 * ox0 - 1;
  float bv0 = sB[0], bv1 = sB[1];
  float a0 = bv0, a1 = bv0, a2 = bv0, a3 = bv0;
  float b0 = bv1, b1 = bv1, b2 = bv1, b3 = bv1;
  size_t ibase = (size_t)(n0 + n) * 49152;
  if (fl) enc1_loop((const float*)patch + ibase, iy0, cx0, sW, a0, a1, a2, a3, b0, b1, b2, b3);
  else    enc1_loop((const bf16*)patch + ibase, iy0, cx0, sW, a0, a1, a2, a3, b0, b1, b2, b3);
  float* op = out + (size_t)(n * 64 + co0) * 4096 + oy * 64 + ox0;
  op[0] = fmaxf(a0, 0.f); op[1] = fmaxf(a1, 0.f);
  op[2] = fmaxf(a2, 0.f); op[3] = fmaxf(a3, 0.f);
  op += 4096;
  op[0] = fmaxf(b0, 0.f); op[1] = fmaxf(b1, 0.f);
  op[2] = fmaxf(b2, 0.f); op[3] = fmaxf(b3, 0.f);
}

// ---------------- enc2: s2 k4, 64ch 64x64 -> 128ch 32x32; 4 co/thread, SKEWED LDS ----------------
// Stride-2 conv => all lane strides even => padding alone caps at 16 banks (4-way).
// Additive skew s(iy)=((iy>>1)&7) with row stride 72 makes bank = 8*iy+s(iy)+ix cover
// all 32 banks across a wave (oy residues distinct mod 8) -> 2-way = free.
__global__ __launch_bounds__(256) void k_enc2(
    const float* __restrict__ in, const void* __restrict__ w,
    const void* __restrict__ bias, float* __restrict__ out,
    const int* __restrict__ flag)
{
  const int Cin = 64, Cout = 128;
  const int P = 72;                          // skewed row stride
  __shared__ __align__(16) float sW[4096];
  __shared__ float sIn[64 * P];              // 18 KB
  int fl = flag[0];
  int bid = blockIdx.x;
  int cp = bid & 31, n = bid >> 5;
  int co0 = cp * 4;
  int tid = threadIdx.x;
  for (int i = tid; i < 4096; i += 256)
    sW[i] = ldg_in(w, co0 * 1024 + i, fl);
  int oy = tid >> 3, ox0 = (tid & 7) << 2;
  float bvA = ldg_in(bias, co0, fl), bvB = ldg_in(bias, co0 + 1, fl);
  float bvC = ldg_in(bias, co0 + 2, fl), bvD = ldg_in(bias, co0 + 3, fl);
  float a0 = bvA, a1 = bvA, a2 = bvA, a3 = bvA;
  float b0 = bvB, b1 = bvB, b2 = bvB, b3 = bvB;
  float c0 = bvC, c1 = bvC, c2 = bvC, c3 = bvC;
  float d0 = bvD, d1 = bvD, d2 = bvD, d3 = bvD;
  int ry0 = 2 * oy - 1;
  int cx0 = 2 * ox0 - 1;
  const float* ip = in + (size_t)n * Cin * 4096;
  for (int ci = 0; ci < Cin; ++ci) {
    __syncthreads();
    {
      const float4* g4 = (const float4*)(ip + ci * 4096);
      #pragma unroll
      for (int j = 0; j < 4; ++j) {
        int i4 = tid + j * 256;
        float4 v = g4[i4];
        int flat = i4 * 4;
        int iy = flat >> 6, ix = flat & 63;
        float* dst = sIn + iy * P + ((iy >> 1) & 7) + ix;
        dst[0] = v.x; dst[1] = v.y; dst[2] = v.z; dst[3] = v.w;
      }
    }
    __syncthreads();
    #pragma unroll
    for (int ky = 0; ky < 4; ++ky) {
      int iy = ry0 + ky;
      if ((unsigned)iy < 64u) {
        const float* rp = sIn + iy * P + ((iy >> 1) & 7);
        float x0 = (cx0 >= 0) ? rp[cx0] : 0.f;
        float x1 = rp[cx0 + 1], x2 = rp[cx0 + 2], x3 = rp[cx0 + 3], x4 = rp[cx0 + 4];
        float x5 = rp[cx0 + 5], x6 = rp[cx0 + 6], x7 = rp[cx0 + 7], x8 = rp[cx0 + 8];
        float x9 = (cx0 + 9 < 64) ? rp[cx0 + 9] : 0.f;
        int wb = ci * 16 + ky * 4;
        {
          float4 wa = *(const float4*)(sW + wb);
          a0 = fmaf(x0, wa.x, fmaf(x1, wa.y, fmaf(x2, wa.z, fmaf(x3, wa.w, a0))));
          a1 = fmaf(x2, wa.x, fmaf(x3, wa.y, fmaf(x4, wa.z, fmaf(x5, wa.w, a1))));
          a2 = fmaf(x4, wa.x, fmaf(x5, wa.y, fmaf(x6, wa.z, fmaf(x7, wa.w, a2))));
          a3 = fmaf(x6, wa.x, fmaf(x7, wa.y, fmaf(x8, wa.z, fmaf(x9, wa.w, a3))));
          float4 wbv = *(const float4*)(sW + wb + 1024);
          b0 = fmaf(x0, wbv.x, fmaf(x1, wbv.y, fmaf(x2, wbv.z, fmaf(x3, wbv.w, b0))));
          b1 = fmaf(x2, wbv.x, fmaf(x3, wbv.y, fmaf(x4, wbv.z, fmaf(x5, wbv.w, b1))));
          b2 = fmaf(x4, wbv.x, fmaf(x5, wbv.y, fmaf(x6, wbv.z, fmaf(x7, wbv.w, b2))));
          b3 = fmaf(x6, wbv.x, fmaf(x7, wbv.y, fmaf(x8, wbv.z, fmaf(x9, wbv.w, b3))));
        }
        {
          float4 wc = *(const float4*)(sW + wb + 2048);
          c0 = fmaf(x0, wc.x, fmaf(x1, wc.y, fmaf(x2, wc.z, fmaf(x3, wc.w, c0))));
          c1 = fmaf(x2, wc.x, fmaf(x3, wc.y, fmaf(x4, wc.z, fmaf(x5, wc.w, c1))));
          c2 = fmaf(x4, wc.x, fmaf(x5, wc.y, fmaf(x6, wc.z, fmaf(x7, wc.w, c2))));
          c3 = fmaf(x6, wc.x, fmaf(x7, wc.y, fmaf(x8, wc.z, fmaf(x9, wc.w, c3))));
          float4 wd = *(const float4*)(sW + wb + 3072);
          d0 = fmaf(x0, wd.x, fmaf(x1, wd.y, fmaf(x2, wd.z, fmaf(x3, wd.w, d0))));
          d1 = fmaf(x2, wd.x, fmaf(x3, wd.y, fmaf(x4, wd.z, fmaf(x5, wd.w, d1))));
          d2 = fmaf(x4, wd.x, fmaf(x5, wd.y, fmaf(x6, wd.z, fmaf(x7, wd.w, d2))));
          d3 = fmaf(x6, wd.x, fmaf(x7, wd.y, fmaf(x8, wd.z, fmaf(x9, wd.w, d3))));
        }
      }
    }
  }
  float* op = out + (size_t)(n * Cout + co0) * 1024 + oy * 32 + ox0;
  op[0] = fmaxf(a0, 0.f); op[1] = fmaxf(a1, 0.f); op[2] = fmaxf(a2, 0.f); op[3] = fmaxf(a3, 0.f);
  op += 1024;
  op[0] = fmaxf(b0, 0.f); op[1] = fmaxf(b1, 0.f); op[2] = fmaxf(b2, 0.f); op[3] = fmaxf(b3, 0.f);
  op += 1024;
  op[0] = fmaxf(c0, 0.f); op[1] = fmaxf(c1, 0.f); op[2] = fmaxf(c2, 0.f); op[3] = fmaxf(c3, 0.f);
  op += 1024;
  op[0] = fmaxf(d0, 0.f); op[1] = fmaxf(d1, 0.f); op[2] = fmaxf(d2, 0.f); op[3] = fmaxf(d3, 0.f);
}

// ---- 3x3 conv s1 p1 @32x32 v4: 1 row x 8 px per thread, 4 co/block, 2 co/thread ----
#define LOAD10(RP) \
  x0 = (ox0 > 0) ? (RP)[ox0 - 1] : 0.f; \
  x1 = (RP)[ox0];     x2 = (RP)[ox0 + 1]; x3 = (RP)[ox0 + 2]; x4 = (RP)[ox0 + 3]; \
  x5 = (RP)[ox0 + 4]; x6 = (RP)[ox0 + 5]; x7 = (RP)[ox0 + 6]; x8 = (RP)[ox0 + 7]; \
  x9 = (ox0 < 24) ? (RP)[ox0 + 8] : 0.f; \
  if (IN_RELU) { \
    x0 = fmaxf(x0, 0.f); x1 = fmaxf(x1, 0.f); x2 = fmaxf(x2, 0.f); x3 = fmaxf(x3, 0.f); \
    x4 = fmaxf(x4, 0.f); x5 = fmaxf(x5, 0.f); x6 = fmaxf(x6, 0.f); x7 = fmaxf(x7, 0.f); \
    x8 = fmaxf(x8, 0.f); x9 = fmaxf(x9, 0.f); \
  }

#define C8(PX, W0, W1, W2) \
  PX##0 = fmaf(x0, W0, fmaf(x1, W1, fmaf(x2, W2, PX##0))); \
  PX##1 = fmaf(x1, W0, fmaf(x2, W1, fmaf(x3, W2, PX##1))); \
  PX##2 = fmaf(x2, W0, fmaf(x3, W1, fmaf(x4, W2, PX##2))); \
  PX##3 = fmaf(x3, W0, fmaf(x4, W1, fmaf(x5, W2, PX##3))); \
  PX##4 = fmaf(x4, W0, fmaf(x5, W1, fmaf(x6, W2, PX##4))); \
  PX##5 = fmaf(x5, W0, fmaf(x6, W1, fmaf(x7, W2, PX##5))); \
  PX##6 = fmaf(x6, W0, fmaf(x7, W1, fmaf(x8, W2, PX##6))); \
  PX##7 = fmaf(x7, W0, fmaf(x8, W1, fmaf(x9, W2, PX##7)));

#define ROW8_AB(KY) \
  C8(A, wa[3*KY], wa[3*KY+1], wa[3*KY+2]) \
  C8(B, wb[3*KY], wb[3*KY+1], wb[3*KY+2])

template<bool IN_RELU, bool TRANS_W, bool OUT_RELU, bool HAS_BIAS>
__global__ __launch_bounds__(256) void k_conv3x3_v4(
    const float* __restrict__ in, const void* __restrict__ w,
    const void* __restrict__ bias, float* __restrict__ out,
    const int* __restrict__ flag, int Cin, int Cout)
{
  const int HW = 1024;
  const int PP = 33;
  const int PLANE = 32 * PP;
  __shared__ float sW[4608];
  __shared__ float sIn[2 * 1056];
  int fl = flag[0];
  int nq = Cout >> 2;
  int bid = blockIdx.x;
  int qc = bid % nq, n = bid / nq;
  int co0 = qc * 4;
  int tid = threadIdx.x;
  int tot = 4 * Cin * 9;
  for (int i = tid; i < tot; i += 256) {
    int cl = i / (Cin * 9), rem = i % (Cin * 9);
    int ci = rem / 9, k = rem % 9;
    int src = TRANS_W ? ((ci * Cout + co0 + cl) * 9 + (8 - k))
                      : (((co0 + cl) * Cin + ci) * 9 + k);
    sW[i] = ldg_in(w, src, fl);
  }
  int cp = tid >> 7;
  int tt = tid & 127;
  int ty = tt >> 2;
  int tx = tt & 3;
  int ox0 = tx * 8;
  int coA = co0 + cp * 2;
  const float* WA = sW + (cp * 2) * Cin * 9;
  const float* WB = WA + Cin * 9;
  float bvA = HAS_BIAS ? ldg_in(bias, coA, fl) : 0.f;
  float bvB = HAS_BIAS ? ldg_in(bias, coA + 1, fl) : 0.f;
  float A0=bvA,A1=bvA,A2=bvA,A3=bvA,A4=bvA,A5=bvA,A6=bvA,A7=bvA;
  float B0=bvB,B1=bvB,B2=bvB,B3=bvB,B4=bvB,B5=bvB,B6=bvB,B7=bvB;
  const float* ip = in + (size_t)n * Cin * HW;
  for (int cb = 0; cb < Cin; cb += 2) {
    __syncthreads();
    {
      const float4* g4 = (const float4*)(ip + cb * HW);
      #pragma unroll
      for (int j = 0; j < 2; ++j) {
        int i4 = tid + j * 256;
        float4 v = g4[i4];
        int flat = i4 * 4;
        int pl = flat >> 10, rem = flat & 1023;
        float* dst = sIn + pl * PLANE + (rem >> 5) * PP + (rem & 31);
        dst[0] = v.x; dst[1] = v.y; dst[2] = v.z; dst[3] = v.w;
      }
    }
    __syncthreads();
    #pragma unroll
    for (int u = 0; u < 2; ++u) {
      int ci = cb + u;
      const float* sP = sIn + u * PLANE;
      const float* wa = WA + ci * 9;
      const float* wb = WB + ci * 9;
      float x0, x1, x2, x3, x4, x5, x6, x7, x8, x9;
      if (ty > 0) {
        LOAD10(sP + (ty - 1) * PP)
        ROW8_AB(0)
      }
      {
        LOAD10(sP + ty * PP)
        ROW8_AB(1)
      }
      if (ty < 31) {
        LOAD10(sP + (ty + 1) * PP)
        ROW8_AB(2)
      }
    }
  }
  float* op = out + (size_t)(n * Cout + coA) * HW + ty * 32 + ox0;
  if (OUT_RELU) {
    op[0] = fmaxf(A0, 0.f); op[1] = fmaxf(A1, 0.f); op[2] = fmaxf(A2, 0.f); op[3] = fmaxf(A3, 0.f);
    op[4] = fmaxf(A4, 0.f); op[5] = fmaxf(A5, 0.f); op[6] = fmaxf(A6, 0.f); op[7] = fmaxf(A7, 0.f);
    op += HW;
    op[0] = fmaxf(B0, 0.f); op[1] = fmaxf(B1, 0.f); op[2] = fmaxf(B2, 0.f); op[3] = fmaxf(B3, 0.f);
    op[4] = fmaxf(B4, 0.f); op[5] = fmaxf(B5, 0.f); op[6] = fmaxf(B6, 0.f); op[7] = fmaxf(B7, 0.f);
  } else {
    op[0] = A0; op[1] = A1; op[2] = A2; op[3] = A3;
    op[4] = A4; op[5] = A5; op[6] = A6; op[7] = A7;
    op += HW;
    op[0] = B0; op[1] = B1; op[2] = B2; op[3] = B3;
    op[4] = B4; op[5] = B5; op[6] = B6; op[7] = B7;
  }
}

// ---------------- 1x1 conv @32x32: 4co x 4p register tile ----------------
template<bool ACCUM, bool HAS_BIAS, bool OUT_RELU>
__global__ __launch_bounds__(256) void k_conv1x1_t4(
    const float* __restrict__ in, const void* __restrict__ w,
    const void* __restrict__ bias, float* __restrict__ out,
    const int* __restrict__ flag, int Cin, int Cout)
{
  const int HW = 1024;
  __shared__ float sW[512];
  int fl = flag[0];
  int nq = Cout >> 2;
  int bid = blockIdx.x;
  int qc = bid % nq, n = bid / nq;
  int co0 = qc * 4;
  int tid = threadIdx.x;
  for (int i = tid; i < 4 * Cin; i += 256)
    sW[i] = ldg_in(w, co0 * Cin + i, fl);
  __syncthreads();
  float acc[4][4];
  #pragma unroll
  for (int c = 0; c < 4; ++c) {
    float bv = HAS_BIAS ? ldg_in(bias, co0 + c, fl) : 0.f;
    #pragma unroll
    for (int k = 0; k < 4; ++k) acc[c][k] = bv;
  }
  const float* ip = in + (size_t)n * Cin * HW + tid;
  for (int ci = 0; ci < Cin; ++ci) {
    const float* p = ip + ci * HW;
    float x0 = p[0], x1 = p[256], x2 = p[512], x3 = p[768];
    #pragma unroll
    for (int c = 0; c < 4; ++c) {
      float wv = sW[c * Cin + ci];
      acc[c][0] = fmaf(wv, x0, acc[c][0]);
      acc[c][1] = fmaf(wv, x1, acc[c][1]);
      acc[c][2] = fmaf(wv, x2, acc[c][2]);
      acc[c][3] = fmaf(wv, x3, acc[c][3]);
    }
  }
  #pragma unroll
  for (int c = 0; c < 4; ++c) {
    float* op = out + (size_t)(n * Cout + co0 + c) * HW + tid;
    #pragma unroll
    for (int k = 0; k < 4; ++k) {
      float v = acc[c][k];
      if (ACCUM) v += op[k * 256];
      if (OUT_RELU) v = fmaxf(v, 0.f);
      op[k * 256] = v;
    }
  }
}

// ---- ConvTranspose s2 k4 p1 parity-quad macros ----
#define LOADW16V(BASE) { \
  const float4* w4_ = (const float4*)(BASE); \
  float4 t0_ = w4_[0], t1_ = w4_[1], t2_ = w4_[2], t3_ = w4_[3]; \
  w00 = t0_.x; w01 = t0_.y; w02 = t0_.z; w03 = t0_.w; \
  w10 = t1_.x; w11 = t1_.y; w12 = t1_.z; w13 = t1_.w; \
  w20 = t2_.x; w21 = t2_.y; w22 = t2_.z; w23 = t2_.w; \
  w30 = t3_.x; w31 = t3_.y; w32 = t3_.z; w33 = t3_.w; }

#define CT_J(P00, P01, P10, P11, M0, M1, M2, C0, C1, C2, D0, D1, D2) \
  P00 = fmaf(w11, C1, fmaf(w13, C0, fmaf(w31, M1, fmaf(w33, M0, P00)))); \
  P01 = fmaf(w10, C2, fmaf(w12, C1, fmaf(w30, M2, fmaf(w32, M1, P01)))); \
  P10 = fmaf(w01, D1, fmaf(w03, D0, fmaf(w21, C1, fmaf(w23, C0, P10)))); \
  P11 = fmaf(w00, D2, fmaf(w02, D1, fmaf(w20, C2, fmaf(w22, C1, P11))));

#define DECL16(PX, BV) \
  float PX##A0=BV, PX##A1=BV, PX##A2=BV, PX##A3=BV, \
        PX##B0=BV, PX##B1=BV, PX##B2=BV, PX##B3=BV, \
        PX##C0=BV, PX##C1=BV, PX##C2=BV, PX##C3=BV, \
        PX##D0=BV, PX##D1=BV, PX##D2=BV, PX##D3=BV;

#define CT_CO(PX) \
  CT_J(PX##A0, PX##B0, PX##C0, PX##D0, m0, m1, m2, c0, c1, c2, d0, d1, d2) \
  CT_J(PX##A1, PX##B1, PX##C1, PX##D1, m1, m2, m3, c1, c2, c3, d1, d2, d3) \
  CT_J(PX##A2, PX##B2, PX##C2, PX##D2, m2, m3, m4, c2, c3, c4, d2, d3, d4) \
  CT_J(PX##A3, PX##B3, PX##C3, PX##D3, m3, m4, m5, c3, c4, c5, d3, d4, d5)

#define CT_STORE(PX, PTR, HO) \
  (PTR)[0] = fmaxf(PX##A0, 0.f); (PTR)[1] = fmaxf(PX##B0, 0.f); \
  (PTR)[2] = fmaxf(PX##A1, 0.f); (PTR)[3] = fmaxf(PX##B1, 0.f); \
  (PTR)[4] = fmaxf(PX##A2, 0.f); (PTR)[5] = fmaxf(PX##B2, 0.f); \
  (PTR)[6] = fmaxf(PX##A3, 0.f); (PTR)[7] = fmaxf(PX##B3, 0.f); \
  (PTR)[HO]     = fmaxf(PX##C0, 0.f); (PTR)[HO + 1] = fmaxf(PX##D0, 0.f); \
  (PTR)[HO + 2] = fmaxf(PX##C1, 0.f); (PTR)[HO + 3] = fmaxf(PX##D1, 0.f); \
  (PTR)[HO + 4] = fmaxf(PX##C2, 0.f); (PTR)[HO + 5] = fmaxf(PX##D2, 0.f); \
  (PTR)[HO + 6] = fmaxf(PX##C3, 0.f); (PTR)[HO + 7] = fmaxf(PX##D3, 0.f);

// ---------------- up1: convT s2 k4, 128ch 32x32 -> 64ch 64x64, 4 co/thread, staged input ----
__global__ __launch_bounds__(256) void k_convT_up1(
    const float* __restrict__ in, const void* __restrict__ w,
    const void* __restrict__ bias, float* __restrict__ out,
    const int* __restrict__ flag)
{
  const int Cin = 128, Cout = 64;
  const int PP = 33;
  __shared__ __align__(16) float sW[8192];
  __shared__ float sIn[32 * PP];
  int fl = flag[0];
  int bid = blockIdx.x;
  int cp = bid & 15, n = bid >> 4;
  int co0 = cp * 4;
  int tid = threadIdx.x;
  for (int i = tid; i < 8192; i += 256) {
    int cl = i >> 11, rem = i & 2047;
    int ci = rem >> 4, k = rem & 15;
    sW[i] = ldg_in(w, (ci * Cout + co0 + cl) * 16 + k, fl);
  }
  int qa = tid >> 3;
  int qb0 = (tid & 7) * 4;
  float bv0 = ldg_in(bias, co0, fl), bv1 = ldg_in(bias, co0 + 1, fl);
  float bv2 = ldg_in(bias, co0 + 2, fl), bv3 = ldg_in(bias, co0 + 3, fl);
  DECL16(u, bv0) DECL16(v, bv1) DECL16(y, bv2) DECL16(z, bv3)
  const float* ip = in + (size_t)n * Cin * 1024;
  bool vm = qa >= 1, vd = qa + 1 < 32;
  bool vl = qb0 > 0, vr = qb0 < 28;
  for (int ci = 0; ci < Cin; ++ci) {
    __syncthreads();
    {
      float4 g = ((const float4*)(ip + ci * 1024))[tid];
      float* dst = sIn + (tid >> 3) * PP + (tid & 7) * 4;
      dst[0] = g.x; dst[1] = g.y; dst[2] = g.z; dst[3] = g.w;
    }
    __syncthreads();
    const float* rm = sIn + (qa - 1) * PP;
    const float* rc = sIn + qa * PP;
    const float* rd = sIn + (qa + 1) * PP;
    float m0 = (vm && vl) ? rm[qb0 - 1] : 0.f;
    float m1 = vm ? rm[qb0] : 0.f, m2 = vm ? rm[qb0 + 1] : 0.f;
    float m3 = vm ? rm[qb0 + 2] : 0.f, m4 = vm ? rm[qb0 + 3] : 0.f;
    float m5 = (vm && vr) ? rm[qb0 + 4] : 0.f;
    float c0 = vl ? rc[qb0 - 1] : 0.f;
    float c1 = rc[qb0], c2 = rc[qb0 + 1], c3 = rc[qb0 + 2], c4 = rc[qb0 + 3];
    float c5 = vr ? rc[qb0 + 4] : 0.f;
    float d0 = (vd && vl) ? rd[qb0 - 1] : 0.f;
    float d1 = vd ? rd[qb0] : 0.f, d2 = vd ? rd[qb0 + 1] : 0.f;
    float d3 = vd ? rd[qb0 + 2] : 0.f, d4 = vd ? rd[qb0 + 3] : 0.f;
    float d5 = (vd && vr) ? rd[qb0 + 4] : 0.f;
    float w00, w01, w02, w03, w10, w11, w12, w13, w20, w21, w22, w23, w30, w31, w32, w33;
    { LOADW16V(sW + ci * 16)        CT_CO(u) }
    { LOADW16V(sW + 2048 + ci * 16) CT_CO(v) }
    { LOADW16V(sW + 4096 + ci * 16) CT_CO(y) }
    { LOADW16V(sW + 6144 + ci * 16) CT_CO(z) }
  }
  float* op = out + ((size_t)(n * Cout + co0) * 64 + 2 * qa) * 64 + 2 * qb0;
  CT_STORE(u, op, 64) op += (size_t)64 * 64;
  CT_STORE(v, op, 64) op += (size_t)64 * 64;
  CT_STORE(y, op, 64) op += (size_t)64 * 64;
  CT_STORE(z, op, 64)
}

// ---------------- up2: convT s2 k4, 64ch 64x64 -> 3ch 128x128, all 3 co/thread ----------------
__global__ __launch_bounds__(256) void k_convT_up2(
    const float* __restrict__ in, const void* __restrict__ w,
    const void* __restrict__ bias, float* __restrict__ out,
    const int* __restrict__ flag)
{
  const int Cin = 64;
  __shared__ __align__(16) float sW[3072];
  int fl = flag[0];
  int bid = blockIdx.x;
  int s = bid & 7, n = bid >> 3;
  int tid = threadIdx.x;
  for (int i = tid; i < 3072; i += 256)
    sW[i] = ldg_in(w, i, fl);
  __syncthreads();
  int qa = s * 8 + (tid >> 5);
  int qb0 = (tid & 31) * 2;
  float bp = ldg_in(bias, 0, fl), bq = ldg_in(bias, 1, fl), br = ldg_in(bias, 2, fl);
  float pA0 = bp, pA1 = bp, pB0 = bp, pB1 = bp, pC0 = bp, pC1 = bp, pD0 = bp, pD1 = bp;
  float qA0 = bq, qA1 = bq, qB0_ = bq, qB1 = bq, qC0 = bq, qC1 = bq, qD0 = bq, qD1 = bq;
  float rA0 = br, rA1 = br, rB0 = br, rB1 = br, rC0 = br, rC1 = br, rD0 = br, rD1 = br;
  const float* ip = in + (size_t)n * Cin * 4096;
  bool vm = qa >= 1, vd = qa + 1 < 64;
  bool vl = qb0 > 0, vr = qb0 < 62;
  for (int ci = 0; ci < Cin; ++ci) {
    const float* p = ip + ci * 4096;
    const float* rm = p + (qa - 1) * 64;
    const float* rc = p + qa * 64;
    const float* rd = p + (qa + 1) * 64;
    float m0 = (vm && vl) ? rm[qb0 - 1] : 0.f;
    float m1 = vm ? rm[qb0] : 0.f, m2 = vm ? rm[qb0 + 1] : 0.f;
    float m3 = (vm && vr) ? rm[qb0 + 2] : 0.f;
    float c0 = vl ? rc[qb0 - 1] : 0.f;
    float c1 = rc[qb0], c2 = rc[qb0 + 1];
    float c3 = vr ? rc[qb0 + 2] : 0.f;
    float d0 = (vd && vl) ? rd[qb0 - 1] : 0.f;
    float d1 = vd ? rd[qb0] : 0.f, d2 = vd ? rd[qb0 + 1] : 0.f;
    float d3 = (vd && vr) ? rd[qb0 + 2] : 0.f;
    float w00, w01, w02, w03, w10, w11, w12, w13, w20, w21, w22, w23, w30, w31, w32, w33;
    {
      LOADW16V(sW + ci * 48)
      CT_J(pA0, pB0, pC0, pD0, m0, m1, m2, c0, c1, c2, d0, d1, d2)
      CT_J(pA1, pB1, pC1, pD1, m1, m2, m3, c1, c2, c3, d1, d2, d3)
    }
    {
      LOADW16V(sW + ci * 48 + 16)
      CT_J(qA0, qB0_, qC0, qD0, m0, m1, m2, c0, c1, c2, d0, d1, d2)
      CT_J(qA1, qB1, qC1, qD1, m1, m2, m3, c1, c2, c3, d1, d2, d3)
    }
    {
      LOADW16V(sW + ci * 48 + 32)
      CT_J(rA0, rB0, rC0, rD0, m0, m1, m2, c0, c1, c2, d0, d1, d2)
      CT_J(rA1, rB1, rC1, rD1, m1, m2, m3, c1, c2, c3, d1, d2, d3)
    }
  }
  float* op = out + ((size_t)(n * 3 + 0) * 128 + 2 * qa) * 128 + 2 * qb0;
  op[0] = pA0; op[1] = pB0; op[2] = pA1; op[3] = pB1;
  op[128] = pC0; op[129] = pD0; op[130] = pC1; op[131] = pD1;
  op += (size_t)128 * 128;
  op[0] = qA0; op[1] = qB0_; op[2] = qA1; op[3] = qB1;
  op[128] = qC0; op[129] = qD0; op[130] = qC1; op[131] = qD1;
  op += (size_t)128 * 128;
  op[0] = rA0; op[1] = rB0; op[2] = rA1; op[3] = rB1;
  op[128] = rC0; op[129] = rD0; op[130] = rC1; op[131] = rD1;
}

// ---------------- VQ phase 1: per-chunk argmin (256 codebook rows per chunk) ----------------
__global__ __launch_bounds__(256) void k_vq1(
    const float* __restrict__ z, const void* __restrict__ emb,
    const int* __restrict__ flag, float* __restrict__ distb, float* __restrict__ idxb)
{
  const int PE = 65;
  __shared__ float sE[128 * PE];
  __shared__ float sEE[128];
  int fl = flag[0];
  int tid = threadIdx.x;
  int bid = blockIdx.x;
  int ch = bid & 3, vb = bid >> 2;
  int n = vb * 256 + tid;
  int nb = n >> 10, p = n & 1023;
  const float* zp = z + nb * 65536 + p;
  float zv[64];
  float zz = 0.f;
  #pragma unroll
  for (int d = 0; d < 64; ++d) { zv[d] = zp[d * 1024]; zz = fmaf(zv[d], zv[d], zz); }
  float best = 3.4e38f; int bidx = ch * 256;
  for (int kb = ch * 2; kb < ch * 2 + 2; ++kb) {
    __syncthreads();
    for (int i = tid; i < 8192; i += 256)
      sE[(i >> 6) * PE + (i & 63)] = ldg_in(emb, kb * 8192 + i, fl);
    __syncthreads();
    if (tid < 128) {
      const float* ep = sE + tid * PE;
      float s = 0.f;
      #pragma unroll
      for (int d = 0; d < 64; ++d) s = fmaf(ep[d], ep[d], s);
      sEE[tid] = s;
    }
    __syncthreads();
    for (int k = 0; k < 128; ++k) {
      const float* ep = sE + k * PE;
      float dot = 0.f;
      #pragma unroll
      for (int d = 0; d < 64; ++d) dot = fmaf(zv[d], ep[d], dot);
      float dist = zz + sEE[k] - 2.f * dot;
      if (dist < best) { best = dist; bidx = kb * 128 + k; }  // strict <: first min wins
    }
  }
  distb[ch * 65536 + n] = best;
  idxb[ch * 65536 + n] = (float)bidx;
}

// ---------------- VQ phase 2: combine chunks, gather zq, loss partials ----------------
__global__ __launch_bounds__(256) void k_vq2(
    const float* __restrict__ z, const void* __restrict__ emb,
    const int* __restrict__ flag, const float* __restrict__ distb,
    const float* __restrict__ idxb, float* __restrict__ zq,
    float* __restrict__ idx_out, float* __restrict__ lossp, int lossbase)
{
  __shared__ float wsum[4];
  int fl = flag[0];
  int tid = threadIdx.x;
  int n = blockIdx.x * 256 + tid;
  float best = distb[n];
  int bidx = (int)idxb[n];
  #pragma unroll
  for (int c = 1; c < 4; ++c) {
    float d = distb[c * 65536 + n];
    if (d < best) { best = d; bidx = (int)idxb[c * 65536 + n]; }  // earlier chunk wins ties
  }
  idx_out[n] = (float)bidx;
  int nb = n >> 10, p = n & 1023;
  const float* zp = z + nb * 65536 + p;
  float* qp = zq + nb * 65536 + p;
  float ls = 0.f;
  #pragma unroll
  for (int d = 0; d < 64; ++d) {
    float e = ldg_in(emb, bidx * 64 + d, fl);
    float zvd = zp[d * 1024];
    qp[d * 1024] = e;
    float df = e - zvd;
    ls = fmaf(df, df, ls);
  }
  #pragma unroll
  for (int off = 32; off > 0; off >>= 1) ls += __shfl_down(ls, off);
  if ((tid & 63) == 0) wsum[tid >> 6] = ls;
  __syncthreads();
  if (tid == 0) lossp[lossbase + blockIdx.x] = wsum[0] + wsum[1] + wsum[2] + wsum[3];
}

__global__ void k_loss_final(const float* __restrict__ lossp, float* __restrict__ out) {
  if (threadIdx.x == 0 && blockIdx.x == 0) {
    float s = 0.f;
    for (int i = 0; i < 256; ++i) s += lossp[i];
    float L = s * (1.f / 4194304.f);
    out[R_RECON + 0] = L;
    out[R_RECON + 1] = L;
  }
}

extern "C" void kernel_launch(void* const* d_in, const int* in_sizes, int n_in,
                              void* d_out, int out_size, void* d_ws, size_t ws_size,
                              hipStream_t stream)
{
  float* out = (float*)d_out;          // fp32 output (established R8-R10)

  float* F = (float*)d_ws;
  float* LOSSP = F;
  int* FLAG = (int*)(F + 256);
  float* VQD = F + 272;
  float* VQI = VQD + 262144;
  float* A = VQI + 262144;

  int Bc = 64;
  while (Bc > 1 && 4ull * (272ull + 524288ull + (size_t)Bc * 393216ull) > ws_size) Bc >>= 1;
  float* H1 = A;
  float* H2 = A + (size_t)Bc * 262144;
  float* H3 = A;
  float* T  = A + (size_t)Bc * 131072;
  float* Z  = A + (size_t)Bc * 163840;
  float* D1 = H2;
  float* D2 = A;

  const void* patch = d_in[0];
  const void* ew1 = d_in[1];  const void* eb1 = d_in[2];
  const void* ew2 = d_in[3];  const void* eb2 = d_in[4];
  const void* ew3 = d_in[5];  const void* eb3 = d_in[6];
  const void* er1a = d_in[7]; const void* er1b = d_in[8];
  const void* er2a = d_in[9]; const void* er2b = d_in[10];
  const void* pqw = d_in[11]; const void* pqb = d_in[12];
  const void* emb = d_in[13];
  const void* dw1 = d_in[14]; const void* db1 = d_in[15];
  const void* dr1a = d_in[16]; const void* dr1b = d_in[17];
  const void* dr2a = d_in[18]; const void* dr2b = d_in[19];
  const void* dw2 = d_in[20]; const void* db2 = d_in[21];
  const void* dw3 = d_in[22]; const void* db3 = d_in[23];

  k_detect<<<1, 256, 0, stream>>>((const u16*)patch, FLAG);

  int NC = 64 / Bc;
  for (int c = 0; c < NC; ++c) {
    int b0 = c * Bc;

    // ---- encoder ----
    k_enc1<<<Bc * 128, 256, 0, stream>>>(patch, ew1, eb1, H1, FLAG, b0);
    k_enc2<<<Bc * 32, 256, 0, stream>>>(H1, ew2, eb2, H2, FLAG);
    k_conv3x3_v4<false, false, false, true><<<Bc * 32, 256, 0, stream>>>(H2, ew3, eb3, H3, FLAG, 128, 128);
    k_conv3x3_v4<true, false, true, false><<<Bc * 8, 256, 0, stream>>>(H3, er1a, nullptr, T, FLAG, 128, 32);
    k_conv1x1_t4<true, false, false><<<Bc * 32, 256, 0, stream>>>(T, er1b, nullptr, H3, FLAG, 32, 128);
    k_conv3x3_v4<true, false, true, false><<<Bc * 8, 256, 0, stream>>>(H3, er2a, nullptr, T, FLAG, 128, 32);
    k_conv1x1_t4<true, false, true><<<Bc * 32, 256, 0, stream>>>(T, er2b, nullptr, H3, FLAG, 32, 128);
    k_conv1x1_t4<false, true, false><<<Bc * 16, 256, 0, stream>>>(H3, pqw, pqb, Z, FLAG, 128, 64);

    // ---- VQ ----
    k_vq1<<<Bc * 16, 256, 0, stream>>>(Z, emb, FLAG, VQD, VQI);
    k_vq2<<<Bc * 4, 256, 0, stream>>>(Z, emb, FLAG, VQD, VQI, Z,
                                      out + R_RECON + 2 + (size_t)b0 * 1024, LOSSP, b0 * 4);

    // ---- decoder ----
    k_conv3x3_v4<false, true, false, true><<<Bc * 32, 256, 0, stream>>>(Z, dw1, db1, D1, FLAG, 64, 128);
    k_conv3x3_v4<true, false, true, false><<<Bc * 8, 256, 0, stream>>>(D1, dr1a, nullptr, T, FLAG, 128, 32);
    k_conv1x1_t4<true, false, false><<<Bc * 32, 256, 0, stream>>>(T, dr1b, nullptr, D1, FLAG, 32, 128);
    k_conv3x3_v4<true, false, true, false><<<Bc * 8, 256, 0, stream>>>(D1, dr2a, nullptr, T, FLAG, 128, 32);
    k_conv1x1_t4<true, false, true><<<Bc * 32, 256, 0, stream>>>(T, dr2b, nullptr, D1, FLAG, 32, 128);
    k_convT_up1<<<Bc * 16, 256, 0, stream>>>(D1, dw2, db2, D2, FLAG);
    k_convT_up2<<<Bc * 8, 256, 0, stream>>>(D2, dw3, db3, out + (size_t)b0 * 49152, FLAG);
  }

  k_loss_final<<<1, 64, 0, stream>>>(LOSSP, out);
}

// Round 22
// 2128.469 us; speedup vs baseline: 1.0198x; 1.0198x over previous
//
#include <hip/hip_runtime.h>
#include <hip/hip_bf16.h>

typedef __hip_bfloat16 bf16;
typedef unsigned short u16;

#define R_RECON 3145728
#define N_IDX   65536

__device__ __forceinline__ float ldg_in(const void* p, int i, int fl) {
  return fl ? ((const float*)p)[i] : __bfloat162float(((const bf16*)p)[i]);
}
__device__ __forceinline__ float cvt(float v) { return v; }
__device__ __forceinline__ float cvt(bf16 v) { return __bfloat162float(v); }

__global__ __launch_bounds__(256) void k_detect(const u16* __restrict__ p, int* __restrict__ flag) {
  __shared__ int s;
  if (threadIdx.x == 0) s = 0;
  __syncthreads();
  for (int i = threadIdx.x; i < 4096; i += 256) {
    float f = __uint_as_float(((unsigned)p[i]) << 16);
    if (!(fabsf(f) < 16384.f)) atomicOr(&s, 1);
  }
  __syncthreads();
  if (threadIdx.x == 0) flag[0] = s;
}

// ---------------- enc1: s2 k4 p1, 3ch 128x128 -> 64ch 64x64; 2 co/thread, 4-wide ox ----
template<typename T>
__device__ __forceinline__ void enc1_loop(
    const T* __restrict__ ip, int iy0, int cx0, const float* sW,
    float& a0, float& a1, float& a2, float& a3,
    float& b0, float& b1, float& b2, float& b3)
{
  #pragma unroll
  for (int ci = 0; ci < 3; ++ci) {
    const T* cp = ip + ci * 16384;
    #pragma unroll
    for (int ky = 0; ky < 4; ++ky) {
      int iy = iy0 + ky;
      if ((unsigned)iy < 128u) {
        const T* rp = cp + iy * 128;
        float x0 = (cx0 >= 0) ? cvt(rp[cx0]) : 0.f;
        float x1 = cvt(rp[cx0 + 1]), x2 = cvt(rp[cx0 + 2]);
        float x3 = cvt(rp[cx0 + 3]), x4 = cvt(rp[cx0 + 4]);
        float x5 = cvt(rp[cx0 + 5]), x6 = cvt(rp[cx0 + 6]);
        float x7 = cvt(rp[cx0 + 7]), x8 = cvt(rp[cx0 + 8]);
        float x9 = (cx0 + 9 < 128) ? cvt(rp[cx0 + 9]) : 0.f;
        const float* WA = sW + ci * 16 + ky * 4;
        float wa0 = WA[0], wa1 = WA[1], wa2 = WA[2], wa3 = WA[3];
        a0 = fmaf(x0, wa0, fmaf(x1, wa1, fmaf(x2, wa2, fmaf(x3, wa3, a0))));
        a1 = fmaf(x2, wa0, fmaf(x3, wa1, fmaf(x4, wa2, fmaf(x5, wa3, a1))));
        a2 = fmaf(x4, wa0, fmaf(x5, wa1, fmaf(x6, wa2, fmaf(x7, wa3, a2))));
        a3 = fmaf(x6, wa0, fmaf(x7, wa1, fmaf(x8, wa2, fmaf(x9, wa3, a3))));
        const float* WB = WA + 48;
        float wb0 = WB[0], wb1 = WB[1], wb2 = WB[2], wb3 = WB[3];
        b0 = fmaf(x0, wb0, fmaf(x1, wb1, fmaf(x2, wb2, fmaf(x3, wb3, b0))));
        b1 = fmaf(x2, wb0, fmaf(x3, wb1, fmaf(x4, wb2, fmaf(x5, wb3, b1))));
        b2 = fmaf(x4, wb0, fmaf(x5, wb1, fmaf(x6, wb2, fmaf(x7, wb3, b2))));
        b3 = fmaf(x6, wb0, fmaf(x7, wb1, fmaf(x8, wb2, fmaf(x9, wb3, b3))));
      }
    }
  }
}

__global__ __launch_bounds__(256) void k_enc1(
    const void* __restrict__ patch, const void* __restrict__ w,
    const void* __restrict__ bias, float* __restrict__ out,
    const int* __restrict__ flag, int n0)
{
  __shared__ float sW[96];
  __shared__ float sB[2];
  int fl = flag[0];
  int bid = blockIdx.x;
  int rg = bid & 3; int t = bid >> 2;
  int cp = t & 31;  int n = t >> 5;
  int co0 = cp * 2;
  int tid = threadIdx.x;
  if (tid < 96) sW[tid] = ldg_in(w, co0 * 48 + tid, fl);
  if (tid < 2)  sB[tid] = ldg_in(bias, co0 + tid, fl);
  __syncthreads();
  int ty = tid >> 4, txq = tid & 15;
  int oy = rg * 16 + ty;
  int ox0 = txq * 4;
  int iy0 = 2 * oy - 1, cx0 = 2 * ox0 - 1;
  float bv0 = sB[0], bv1 = sB[1];
  float a0 = bv0, a1 = bv0, a2 = bv0, a3 = bv0;
  float b0 = bv1, b1 = bv1, b2 = bv1, b3 = bv1;
  size_t ibase = (size_t)(n0 + n) * 49152;
  if (fl) enc1_loop((const float*)patch + ibase, iy0, cx0, sW, a0, a1, a2, a3, b0, b1, b2, b3);
  else    enc1_loop((const bf16*)patch + ibase, iy0, cx0, sW, a0, a1, a2, a3, b0, b1, b2, b3);
  float* op = out + (size_t)(n * 64 + co0) * 4096 + oy * 64 + ox0;
  op[0] = fmaxf(a0, 0.f); op[1] = fmaxf(a1, 0.f);
  op[2] = fmaxf(a2, 0.f); op[3] = fmaxf(a3, 0.f);
  op += 4096;
  op[0] = fmaxf(b0, 0.f); op[1] = fmaxf(b1, 0.f);
  op[2] = fmaxf(b2, 0.f); op[3] = fmaxf(b3, 0.f);
}

// ---------------- enc2: s2 k4, 64ch 64x64 -> 128ch 32x32; 4 co/thread, skew v2 ----------------
// R21 lesson: s(iy)=((iy>>1)&7)@P=72 fixed reads but made WRITES 4-way (consecutive-row
// lanes collided). This scheme keeps f(iy) = iy + ((iy>>3)&1) at row stride 65:
//  - writes (4 consecutive rows, ix stride 4): s constant per 8-row group -> 2-way
//  - reads  (rows stride 2, ix stride 8): f mod 8 = {0,2,4,6,1,3,5,7} distinct -> 2-way
__global__ __launch_bounds__(256) void k_enc2(
    const float* __restrict__ in, const void* __restrict__ w,
    const void* __restrict__ bias, float* __restrict__ out,
    const int* __restrict__ flag)
{
  const int Cin = 64, Cout = 128;
  const int P = 65;
  __shared__ __align__(16) float sW[4096];
  __shared__ float sIn[64 * P + 2];
  int fl = flag[0];
  int bid = blockIdx.x;
  int cp = bid & 31, n = bid >> 5;
  int co0 = cp * 4;
  int tid = threadIdx.x;
  for (int i = tid; i < 4096; i += 256)
    sW[i] = ldg_in(w, co0 * 1024 + i, fl);
  int oy = tid >> 3, ox0 = (tid & 7) << 2;
  float bvA = ldg_in(bias, co0, fl), bvB = ldg_in(bias, co0 + 1, fl);
  float bvC = ldg_in(bias, co0 + 2, fl), bvD = ldg_in(bias, co0 + 3, fl);
  float a0 = bvA, a1 = bvA, a2 = bvA, a3 = bvA;
  float b0 = bvB, b1 = bvB, b2 = bvB, b3 = bvB;
  float c0 = bvC, c1 = bvC, c2 = bvC, c3 = bvC;
  float d0 = bvD, d1 = bvD, d2 = bvD, d3 = bvD;
  int ry0 = 2 * oy - 1;
  int cx0 = 2 * ox0 - 1;
  const float* ip = in + (size_t)n * Cin * 4096;
  for (int ci = 0; ci < Cin; ++ci) {
    __syncthreads();
    {
      const float4* g4 = (const float4*)(ip + ci * 4096);
      #pragma unroll
      for (int j = 0; j < 4; ++j) {
        int i4 = tid + j * 256;
        float4 v = g4[i4];
        int flat = i4 * 4;
        int iy = flat >> 6, ix = flat & 63;
        float* dst = sIn + iy * P + ((iy >> 3) & 1) + ix;
        dst[0] = v.x; dst[1] = v.y; dst[2] = v.z; dst[3] = v.w;
      }
    }
    __syncthreads();
    #pragma unroll
    for (int ky = 0; ky < 4; ++ky) {
      int iy = ry0 + ky;
      if ((unsigned)iy < 64u) {
        const float* rp = sIn + iy * P + ((iy >> 3) & 1);
        float x0 = (cx0 >= 0) ? rp[cx0] : 0.f;
        float x1 = rp[cx0 + 1], x2 = rp[cx0 + 2], x3 = rp[cx0 + 3], x4 = rp[cx0 + 4];
        float x5 = rp[cx0 + 5], x6 = rp[cx0 + 6], x7 = rp[cx0 + 7], x8 = rp[cx0 + 8];
        float x9 = (cx0 + 9 < 64) ? rp[cx0 + 9] : 0.f;
        int wb = ci * 16 + ky * 4;
        {
          float4 wa = *(const float4*)(sW + wb);
          a0 = fmaf(x0, wa.x, fmaf(x1, wa.y, fmaf(x2, wa.z, fmaf(x3, wa.w, a0))));
          a1 = fmaf(x2, wa.x, fmaf(x3, wa.y, fmaf(x4, wa.z, fmaf(x5, wa.w, a1))));
          a2 = fmaf(x4, wa.x, fmaf(x5, wa.y, fmaf(x6, wa.z, fmaf(x7, wa.w, a2))));
          a3 = fmaf(x6, wa.x, fmaf(x7, wa.y, fmaf(x8, wa.z, fmaf(x9, wa.w, a3))));
          float4 wbv = *(const float4*)(sW + wb + 1024);
          b0 = fmaf(x0, wbv.x, fmaf(x1, wbv.y, fmaf(x2, wbv.z, fmaf(x3, wbv.w, b0))));
          b1 = fmaf(x2, wbv.x, fmaf(x3, wbv.y, fmaf(x4, wbv.z, fmaf(x5, wbv.w, b1))));
          b2 = fmaf(x4, wbv.x, fmaf(x5, wbv.y, fmaf(x6, wbv.z, fmaf(x7, wbv.w, b2))));
          b3 = fmaf(x6, wbv.x, fmaf(x7, wbv.y, fmaf(x8, wbv.z, fmaf(x9, wbv.w, b3))));
        }
        {
          float4 wc = *(const float4*)(sW + wb + 2048);
          c0 = fmaf(x0, wc.x, fmaf(x1, wc.y, fmaf(x2, wc.z, fmaf(x3, wc.w, c0))));
          c1 = fmaf(x2, wc.x, fmaf(x3, wc.y, fmaf(x4, wc.z, fmaf(x5, wc.w, c1))));
          c2 = fmaf(x4, wc.x, fmaf(x5, wc.y, fmaf(x6, wc.z, fmaf(x7, wc.w, c2))));
          c3 = fmaf(x6, wc.x, fmaf(x7, wc.y, fmaf(x8, wc.z, fmaf(x9, wc.w, c3))));
          float4 wd = *(const float4*)(sW + wb + 3072);
          d0 = fmaf(x0, wd.x, fmaf(x1, wd.y, fmaf(x2, wd.z, fmaf(x3, wd.w, d0))));
          d1 = fmaf(x2, wd.x, fmaf(x3, wd.y, fmaf(x4, wd.z, fmaf(x5, wd.w, d1))));
          d2 = fmaf(x4, wd.x, fmaf(x5, wd.y, fmaf(x6, wd.z, fmaf(x7, wd.w, d2))));
          d3 = fmaf(x6, wd.x, fmaf(x7, wd.y, fmaf(x8, wd.z, fmaf(x9, wd.w, d3))));
        }
      }
    }
  }
  float* op = out + (size_t)(n * Cout + co0) * 1024 + oy * 32 + ox0;
  op[0] = fmaxf(a0, 0.f); op[1] = fmaxf(a1, 0.f); op[2] = fmaxf(a2, 0.f); op[3] = fmaxf(a3, 0.f);
  op += 1024;
  op[0] = fmaxf(b0, 0.f); op[1] = fmaxf(b1, 0.f); op[2] = fmaxf(b2, 0.f); op[3] = fmaxf(b3, 0.f);
  op += 1024;
  op[0] = fmaxf(c0, 0.f); op[1] = fmaxf(c1, 0.f); op[2] = fmaxf(c2, 0.f); op[3] = fmaxf(c3, 0.f);
  op += 1024;
  op[0] = fmaxf(d0, 0.f); op[1] = fmaxf(d1, 0.f); op[2] = fmaxf(d2, 0.f); op[3] = fmaxf(d3, 0.f);
}

// ---- 3x3 conv s1 p1 @32x32 v4: 1 row x 8 px per thread, 4 co/block, 2 co/thread ----
#define LOAD10(RP) \
  x0 = (ox0 > 0) ? (RP)[ox0 - 1] : 0.f; \
  x1 = (RP)[ox0];     x2 = (RP)[ox0 + 1]; x3 = (RP)[ox0 + 2]; x4 = (RP)[ox0 + 3]; \
  x5 = (RP)[ox0 + 4]; x6 = (RP)[ox0 + 5]; x7 = (RP)[ox0 + 6]; x8 = (RP)[ox0 + 7]; \
  x9 = (ox0 < 24) ? (RP)[ox0 + 8] : 0.f; \
  if (IN_RELU) { \
    x0 = fmaxf(x0, 0.f); x1 = fmaxf(x1, 0.f); x2 = fmaxf(x2, 0.f); x3 = fmaxf(x3, 0.f); \
    x4 = fmaxf(x4, 0.f); x5 = fmaxf(x5, 0.f); x6 = fmaxf(x6, 0.f); x7 = fmaxf(x7, 0.f); \
    x8 = fmaxf(x8, 0.f); x9 = fmaxf(x9, 0.f); \
  }

#define C8(PX, W0, W1, W2) \
  PX##0 = fmaf(x0, W0, fmaf(x1, W1, fmaf(x2, W2, PX##0))); \
  PX##1 = fmaf(x1, W0, fmaf(x2, W1, fmaf(x3, W2, PX##1))); \
  PX##2 = fmaf(x2, W0, fmaf(x3, W1, fmaf(x4, W2, PX##2))); \
  PX##3 = fmaf(x3, W0, fmaf(x4, W1, fmaf(x5, W2, PX##3))); \
  PX##4 = fmaf(x4, W0, fmaf(x5, W1, fmaf(x6, W2, PX##4))); \
  PX##5 = fmaf(x5, W0, fmaf(x6, W1, fmaf(x7, W2, PX##5))); \
  PX##6 = fmaf(x6, W0, fmaf(x7, W1, fmaf(x8, W2, PX##6))); \
  PX##7 = fmaf(x7, W0, fmaf(x8, W1, fmaf(x9, W2, PX##7)));

#define ROW8_AB(KY) \
  C8(A, wa[3*KY], wa[3*KY+1], wa[3*KY+2]) \
  C8(B, wb[3*KY], wb[3*KY+1], wb[3*KY+2])

template<bool IN_RELU, bool TRANS_W, bool OUT_RELU, bool HAS_BIAS>
__global__ __launch_bounds__(256) void k_conv3x3_v4(
    const float* __restrict__ in, const void* __restrict__ w,
    const void* __restrict__ bias, float* __restrict__ out,
    const int* __restrict__ flag, int Cin, int Cout)
{
  const int HW = 1024;
  const int PP = 33;
  const int PLANE = 32 * PP;
  __shared__ float sW[4608];
  __shared__ float sIn[2 * 1056];
  int fl = flag[0];
  int nq = Cout >> 2;
  int bid = blockIdx.x;
  int qc = bid % nq, n = bid / nq;
  int co0 = qc * 4;
  int tid = threadIdx.x;
  int tot = 4 * Cin * 9;
  for (int i = tid; i < tot; i += 256) {
    int cl = i / (Cin * 9), rem = i % (Cin * 9);
    int ci = rem / 9, k = rem % 9;
    int src = TRANS_W ? ((ci * Cout + co0 + cl) * 9 + (8 - k))
                      : (((co0 + cl) * Cin + ci) * 9 + k);
    sW[i] = ldg_in(w, src, fl);
  }
  int cp = tid >> 7;
  int tt = tid & 127;
  int ty = tt >> 2;
  int tx = tt & 3;
  int ox0 = tx * 8;
  int coA = co0 + cp * 2;
  const float* WA = sW + (cp * 2) * Cin * 9;
  const float* WB = WA + Cin * 9;
  float bvA = HAS_BIAS ? ldg_in(bias, coA, fl) : 0.f;
  float bvB = HAS_BIAS ? ldg_in(bias, coA + 1, fl) : 0.f;
  float A0=bvA,A1=bvA,A2=bvA,A3=bvA,A4=bvA,A5=bvA,A6=bvA,A7=bvA;
  float B0=bvB,B1=bvB,B2=bvB,B3=bvB,B4=bvB,B5=bvB,B6=bvB,B7=bvB;
  const float* ip = in + (size_t)n * Cin * HW;
  for (int cb = 0; cb < Cin; cb += 2) {
    __syncthreads();
    {
      const float4* g4 = (const float4*)(ip + cb * HW);
      #pragma unroll
      for (int j = 0; j < 2; ++j) {
        int i4 = tid + j * 256;
        float4 v = g4[i4];
        int flat = i4 * 4;
        int pl = flat >> 10, rem = flat & 1023;
        float* dst = sIn + pl * PLANE + (rem >> 5) * PP + (rem & 31);
        dst[0] = v.x; dst[1] = v.y; dst[2] = v.z; dst[3] = v.w;
      }
    }
    __syncthreads();
    #pragma unroll
    for (int u = 0; u < 2; ++u) {
      int ci = cb + u;
      const float* sP = sIn + u * PLANE;
      const float* wa = WA + ci * 9;
      const float* wb = WB + ci * 9;
      float x0, x1, x2, x3, x4, x5, x6, x7, x8, x9;
      if (ty > 0) {
        LOAD10(sP + (ty - 1) * PP)
        ROW8_AB(0)
      }
      {
        LOAD10(sP + ty * PP)
        ROW8_AB(1)
      }
      if (ty < 31) {
        LOAD10(sP + (ty + 1) * PP)
        ROW8_AB(2)
      }
    }
  }
  float* op = out + (size_t)(n * Cout + coA) * HW + ty * 32 + ox0;
  if (OUT_RELU) {
    op[0] = fmaxf(A0, 0.f); op[1] = fmaxf(A1, 0.f); op[2] = fmaxf(A2, 0.f); op[3] = fmaxf(A3, 0.f);
    op[4] = fmaxf(A4, 0.f); op[5] = fmaxf(A5, 0.f); op[6] = fmaxf(A6, 0.f); op[7] = fmaxf(A7, 0.f);
    op += HW;
    op[0] = fmaxf(B0, 0.f); op[1] = fmaxf(B1, 0.f); op[2] = fmaxf(B2, 0.f); op[3] = fmaxf(B3, 0.f);
    op[4] = fmaxf(B4, 0.f); op[5] = fmaxf(B5, 0.f); op[6] = fmaxf(B6, 0.f); op[7] = fmaxf(B7, 0.f);
  } else {
    op[0] = A0; op[1] = A1; op[2] = A2; op[3] = A3;
    op[4] = A4; op[5] = A5; op[6] = A6; op[7] = A7;
    op += HW;
    op[0] = B0; op[1] = B1; op[2] = B2; op[3] = B3;
    op[4] = B4; op[5] = B5; op[6] = B6; op[7] = B7;
  }
}

// ---------------- 1x1 conv @32x32: 4co x 4p register tile ----------------
template<bool ACCUM, bool HAS_BIAS, bool OUT_RELU>
__global__ __launch_bounds__(256) void k_conv1x1_t4(
    const float* __restrict__ in, const void* __restrict__ w,
    const void* __restrict__ bias, float* __restrict__ out,
    const int* __restrict__ flag, int Cin, int Cout)
{
  const int HW = 1024;
  __shared__ float sW[512];
  int fl = flag[0];
  int nq = Cout >> 2;
  int bid = blockIdx.x;
  int qc = bid % nq, n = bid / nq;
  int co0 = qc * 4;
  int tid = threadIdx.x;
  for (int i = tid; i < 4 * Cin; i += 256)
    sW[i] = ldg_in(w, co0 * Cin + i, fl);
  __syncthreads();
  float acc[4][4];
  #pragma unroll
  for (int c = 0; c < 4; ++c) {
    float bv = HAS_BIAS ? ldg_in(bias, co0 + c, fl) : 0.f;
    #pragma unroll
    for (int k = 0; k < 4; ++k) acc[c][k] = bv;
  }
  const float* ip = in + (size_t)n * Cin * HW + tid;
  for (int ci = 0; ci < Cin; ++ci) {
    const float* p = ip + ci * HW;
    float x0 = p[0], x1 = p[256], x2 = p[512], x3 = p[768];
    #pragma unroll
    for (int c = 0; c < 4; ++c) {
      float wv = sW[c * Cin + ci];
      acc[c][0] = fmaf(wv, x0, acc[c][0]);
      acc[c][1] = fmaf(wv, x1, acc[c][1]);
      acc[c][2] = fmaf(wv, x2, acc[c][2]);
      acc[c][3] = fmaf(wv, x3, acc[c][3]);
    }
  }
  #pragma unroll
  for (int c = 0; c < 4; ++c) {
    float* op = out + (size_t)(n * Cout + co0 + c) * HW + tid;
    #pragma unroll
    for (int k = 0; k < 4; ++k) {
      float v = acc[c][k];
      if (ACCUM) v += op[k * 256];
      if (OUT_RELU) v = fmaxf(v, 0.f);
      op[k * 256] = v;
    }
  }
}

// ---- ConvTranspose s2 k4 p1 parity-quad macros ----
#define LOADW16V(BASE) { \
  const float4* w4_ = (const float4*)(BASE); \
  float4 t0_ = w4_[0], t1_ = w4_[1], t2_ = w4_[2], t3_ = w4_[3]; \
  w00 = t0_.x; w01 = t0_.y; w02 = t0_.z; w03 = t0_.w; \
  w10 = t1_.x; w11 = t1_.y; w12 = t1_.z; w13 = t1_.w; \
  w20 = t2_.x; w21 = t2_.y; w22 = t2_.z; w23 = t2_.w; \
  w30 = t3_.x; w31 = t3_.y; w32 = t3_.z; w33 = t3_.w; }

#define CT_J(P00, P01, P10, P11, M0, M1, M2, C0, C1, C2, D0, D1, D2) \
  P00 = fmaf(w11, C1, fmaf(w13, C0, fmaf(w31, M1, fmaf(w33, M0, P00)))); \
  P01 = fmaf(w10, C2, fmaf(w12, C1, fmaf(w30, M2, fmaf(w32, M1, P01)))); \
  P10 = fmaf(w01, D1, fmaf(w03, D0, fmaf(w21, C1, fmaf(w23, C0, P10)))); \
  P11 = fmaf(w00, D2, fmaf(w02, D1, fmaf(w20, C2, fmaf(w22, C1, P11))));

#define DECL16(PX, BV) \
  float PX##A0=BV, PX##A1=BV, PX##A2=BV, PX##A3=BV, \
        PX##B0=BV, PX##B1=BV, PX##B2=BV, PX##B3=BV, \
        PX##C0=BV, PX##C1=BV, PX##C2=BV, PX##C3=BV, \
        PX##D0=BV, PX##D1=BV, PX##D2=BV, PX##D3=BV;

#define CT_CO(PX) \
  CT_J(PX##A0, PX##B0, PX##C0, PX##D0, m0, m1, m2, c0, c1, c2, d0, d1, d2) \
  CT_J(PX##A1, PX##B1, PX##C1, PX##D1, m1, m2, m3, c1, c2, c3, d1, d2, d3) \
  CT_J(PX##A2, PX##B2, PX##C2, PX##D2, m2, m3, m4, c2, c3, c4, d2, d3, d4) \
  CT_J(PX##A3, PX##B3, PX##C3, PX##D3, m3, m4, m5, c3, c4, c5, d3, d4, d5)

#define CT_STORE(PX, PTR, HO) \
  (PTR)[0] = fmaxf(PX##A0, 0.f); (PTR)[1] = fmaxf(PX##B0, 0.f); \
  (PTR)[2] = fmaxf(PX##A1, 0.f); (PTR)[3] = fmaxf(PX##B1, 0.f); \
  (PTR)[4] = fmaxf(PX##A2, 0.f); (PTR)[5] = fmaxf(PX##B2, 0.f); \
  (PTR)[6] = fmaxf(PX##A3, 0.f); (PTR)[7] = fmaxf(PX##B3, 0.f); \
  (PTR)[HO]     = fmaxf(PX##C0, 0.f); (PTR)[HO + 1] = fmaxf(PX##D0, 0.f); \
  (PTR)[HO + 2] = fmaxf(PX##C1, 0.f); (PTR)[HO + 3] = fmaxf(PX##D1, 0.f); \
  (PTR)[HO + 4] = fmaxf(PX##C2, 0.f); (PTR)[HO + 5] = fmaxf(PX##D2, 0.f); \
  (PTR)[HO + 6] = fmaxf(PX##C3, 0.f); (PTR)[HO + 7] = fmaxf(PX##D3, 0.f);

// ---------------- up1: convT s2 k4, 128ch 32x32 -> 64ch 64x64, 4 co/thread, staged input ----
__global__ __launch_bounds__(256) void k_convT_up1(
    const float* __restrict__ in, const void* __restrict__ w,
    const void* __restrict__ bias, float* __restrict__ out,
    const int* __restrict__ flag)
{
  const int Cin = 128, Cout = 64;
  const int PP = 33;
  __shared__ __align__(16) float sW[8192];
  __shared__ float sIn[32 * PP];
  int fl = flag[0];
  int bid = blockIdx.x;
  int cp = bid & 15, n = bid >> 4;
  int co0 = cp * 4;
  int tid = threadIdx.x;
  for (int i = tid; i < 8192; i += 256) {
    int cl = i >> 11, rem = i & 2047;
    int ci = rem >> 4, k = rem & 15;
    sW[i] = ldg_in(w, (ci * Cout + co0 + cl) * 16 + k, fl);
  }
  int qa = tid >> 3;
  int qb0 = (tid & 7) * 4;
  float bv0 = ldg_in(bias, co0, fl), bv1 = ldg_in(bias, co0 + 1, fl);
  float bv2 = ldg_in(bias, co0 + 2, fl), bv3 = ldg_in(bias, co0 + 3, fl);
  DECL16(u, bv0) DECL16(v, bv1) DECL16(y, bv2) DECL16(z, bv3)
  const float* ip = in + (size_t)n * Cin * 1024;
  bool vm = qa >= 1, vd = qa + 1 < 32;
  bool vl = qb0 > 0, vr = qb0 < 28;
  for (int ci = 0; ci < Cin; ++ci) {
    __syncthreads();
    {
      float4 g = ((const float4*)(ip + ci * 1024))[tid];
      float* dst = sIn + (tid >> 3) * PP + (tid & 7) * 4;
      dst[0] = g.x; dst[1] = g.y; dst[2] = g.z; dst[3] = g.w;
    }
    __syncthreads();
    const float* rm = sIn + (qa - 1) * PP;
    const float* rc = sIn + qa * PP;
    const float* rd = sIn + (qa + 1) * PP;
    float m0 = (vm && vl) ? rm[qb0 - 1] : 0.f;
    float m1 = vm ? rm[qb0] : 0.f, m2 = vm ? rm[qb0 + 1] : 0.f;
    float m3 = vm ? rm[qb0 + 2] : 0.f, m4 = vm ? rm[qb0 + 3] : 0.f;
    float m5 = (vm && vr) ? rm[qb0 + 4] : 0.f;
    float c0 = vl ? rc[qb0 - 1] : 0.f;
    float c1 = rc[qb0], c2 = rc[qb0 + 1], c3 = rc[qb0 + 2], c4 = rc[qb0 + 3];
    float c5 = vr ? rc[qb0 + 4] : 0.f;
    float d0 = (vd && vl) ? rd[qb0 - 1] : 0.f;
    float d1 = vd ? rd[qb0] : 0.f, d2 = vd ? rd[qb0 + 1] : 0.f;
    float d3 = vd ? rd[qb0 + 2] : 0.f, d4 = vd ? rd[qb0 + 3] : 0.f;
    float d5 = (vd && vr) ? rd[qb0 + 4] : 0.f;
    float w00, w01, w02, w03, w10, w11, w12, w13, w20, w21, w22, w23, w30, w31, w32, w33;
    { LOADW16V(sW + ci * 16)        CT_CO(u) }
    { LOADW16V(sW + 2048 + ci * 16) CT_CO(v) }
    { LOADW16V(sW + 4096 + ci * 16) CT_CO(y) }
    { LOADW16V(sW + 6144 + ci * 16) CT_CO(z) }
  }
  float* op = out + ((size_t)(n * Cout + co0) * 64 + 2 * qa) * 64 + 2 * qb0;
  CT_STORE(u, op, 64) op += (size_t)64 * 64;
  CT_STORE(v, op, 64) op += (size_t)64 * 64;
  CT_STORE(y, op, 64) op += (size_t)64 * 64;
  CT_STORE(z, op, 64)
}

// ---------------- up2: convT s2 k4, 64ch 64x64 -> 3ch 128x128, all 3 co/thread ----------------
__global__ __launch_bounds__(256) void k_convT_up2(
    const float* __restrict__ in, const void* __restrict__ w,
    const void* __restrict__ bias, float* __restrict__ out,
    const int* __restrict__ flag)
{
  const int Cin = 64;
  __shared__ __align__(16) float sW[3072];
  int fl = flag[0];
  int bid = blockIdx.x;
  int s = bid & 7, n = bid >> 3;
  int tid = threadIdx.x;
  for (int i = tid; i < 3072; i += 256)
    sW[i] = ldg_in(w, i, fl);
  __syncthreads();
  int qa = s * 8 + (tid >> 5);
  int qb0 = (tid & 31) * 2;
  float bp = ldg_in(bias, 0, fl), bq = ldg_in(bias, 1, fl), br = ldg_in(bias, 2, fl);
  float pA0 = bp, pA1 = bp, pB0 = bp, pB1 = bp, pC0 = bp, pC1 = bp, pD0 = bp, pD1 = bp;
  float qA0 = bq, qA1 = bq, qB0_ = bq, qB1 = bq, qC0 = bq, qC1 = bq, qD0 = bq, qD1 = bq;
  float rA0 = br, rA1 = br, rB0 = br, rB1 = br, rC0 = br, rC1 = br, rD0 = br, rD1 = br;
  const float* ip = in + (size_t)n * Cin * 4096;
  bool vm = qa >= 1, vd = qa + 1 < 64;
  bool vl = qb0 > 0, vr = qb0 < 62;
  for (int ci = 0; ci < Cin; ++ci) {
    const float* p = ip + ci * 4096;
    const float* rm = p + (qa - 1) * 64;
    const float* rc = p + qa * 64;
    const float* rd = p + (qa + 1) * 64;
    float m0 = (vm && vl) ? rm[qb0 - 1] : 0.f;
    float m1 = vm ? rm[qb0] : 0.f, m2 = vm ? rm[qb0 + 1] : 0.f;
    float m3 = (vm && vr) ? rm[qb0 + 2] : 0.f;
    float c0 = vl ? rc[qb0 - 1] : 0.f;
    float c1 = rc[qb0], c2 = rc[qb0 + 1];
    float c3 = vr ? rc[qb0 + 2] : 0.f;
    float d0 = (vd && vl) ? rd[qb0 - 1] : 0.f;
    float d1 = vd ? rd[qb0] : 0.f, d2 = vd ? rd[qb0 + 1] : 0.f;
    float d3 = (vd && vr) ? rd[qb0 + 2] : 0.f;
    float w00, w01, w02, w03, w10, w11, w12, w13, w20, w21, w22, w23, w30, w31, w32, w33;
    {
      LOADW16V(sW + ci * 48)
      CT_J(pA0, pB0, pC0, pD0, m0, m1, m2, c0, c1, c2, d0, d1, d2)
      CT_J(pA1, pB1, pC1, pD1, m1, m2, m3, c1, c2, c3, d1, d2, d3)
    }
    {
      LOADW16V(sW + ci * 48 + 16)
      CT_J(qA0, qB0_, qC0, qD0, m0, m1, m2, c0, c1, c2, d0, d1, d2)
      CT_J(qA1, qB1, qC1, qD1, m1, m2, m3, c1, c2, c3, d1, d2, d3)
    }
    {
      LOADW16V(sW + ci * 48 + 32)
      CT_J(rA0, rB0, rC0, rD0, m0, m1, m2, c0, c1, c2, d0, d1, d2)
      CT_J(rA1, rB1, rC1, rD1, m1, m2, m3, c1, c2, c3, d1, d2, d3)
    }
  }
  float* op = out + ((size_t)(n * 3 + 0) * 128 + 2 * qa) * 128 + 2 * qb0;
  op[0] = pA0; op[1] = pB0; op[2] = pA1; op[3] = pB1;
  op[128] = pC0; op[129] = pD0; op[130] = pC1; op[131] = pD1;
  op += (size_t)128 * 128;
  op[0] = qA0; op[1] = qB0_; op[2] = qA1; op[3] = qB1;
  op[128] = qC0; op[129] = qD0; op[130] = qC1; op[131] = qD1;
  op += (size_t)128 * 128;
  op[0] = rA0; op[1] = rB0; op[2] = rA1; op[3] = rB1;
  op[128] = rC0; op[129] = rD0; op[130] = rC1; op[131] = rD1;
}

// ---------------- VQ phase 1: per-chunk argmin (256 codebook rows per chunk) ----------------
__global__ __launch_bounds__(256) void k_vq1(
    const float* __restrict__ z, const void* __restrict__ emb,
    const int* __restrict__ flag, float* __restrict__ distb, float* __restrict__ idxb)
{
  const int PE = 65;
  __shared__ float sE[128 * PE];
  __shared__ float sEE[128];
  int fl = flag[0];
  int tid = threadIdx.x;
  int bid = blockIdx.x;
  int ch = bid & 3, vb = bid >> 2;
  int n = vb * 256 + tid;
  int nb = n >> 10, p = n & 1023;
  const float* zp = z + nb * 65536 + p;
  float zv[64];
  float zz = 0.f;
  #pragma unroll
  for (int d = 0; d < 64; ++d) { zv[d] = zp[d * 1024]; zz = fmaf(zv[d], zv[d], zz); }
  float best = 3.4e38f; int bidx = ch * 256;
  for (int kb = ch * 2; kb < ch * 2 + 2; ++kb) {
    __syncthreads();
    for (int i = tid; i < 8192; i += 256)
      sE[(i >> 6) * PE + (i & 63)] = ldg_in(emb, kb * 8192 + i, fl);
    __syncthreads();
    if (tid < 128) {
      const float* ep = sE + tid * PE;
      float s = 0.f;
      #pragma unroll
      for (int d = 0; d < 64; ++d) s = fmaf(ep[d], ep[d], s);
      sEE[tid] = s;
    }
    __syncthreads();
    for (int k = 0; k < 128; ++k) {
      const float* ep = sE + k * PE;
      float dot = 0.f;
      #pragma unroll
      for (int d = 0; d < 64; ++d) dot = fmaf(zv[d], ep[d], dot);
      float dist = zz + sEE[k] - 2.f * dot;
      if (dist < best) { best = dist; bidx = kb * 128 + k; }  // strict <: first min wins
    }
  }
  distb[ch * 65536 + n] = best;
  idxb[ch * 65536 + n] = (float)bidx;
}

// ---------------- VQ phase 2: combine chunks, gather zq, loss partials ----------------
__global__ __launch_bounds__(256) void k_vq2(
    const float* __restrict__ z, const void* __restrict__ emb,
    const int* __restrict__ flag, const float* __restrict__ distb,
    const float* __restrict__ idxb, float* __restrict__ zq,
    float* __restrict__ idx_out, float* __restrict__ lossp, int lossbase)
{
  __shared__ float wsum[4];
  int fl = flag[0];
  int tid = threadIdx.x;
  int n = blockIdx.x * 256 + tid;
  float best = distb[n];
  int bidx = (int)idxb[n];
  #pragma unroll
  for (int c = 1; c < 4; ++c) {
    float d = distb[c * 65536 + n];
    if (d < best) { best = d; bidx = (int)idxb[c * 65536 + n]; }  // earlier chunk wins ties
  }
  idx_out[n] = (float)bidx;
  int nb = n >> 10, p = n & 1023;
  const float* zp = z + nb * 65536 + p;
  float* qp = zq + nb * 65536 + p;
  float ls = 0.f;
  #pragma unroll
  for (int d = 0; d < 64; ++d) {
    float e = ldg_in(emb, bidx * 64 + d, fl);
    float zvd = zp[d * 1024];
    qp[d * 1024] = e;
    float df = e - zvd;
    ls = fmaf(df, df, ls);
  }
  #pragma unroll
  for (int off = 32; off > 0; off >>= 1) ls += __shfl_down(ls, off);
  if ((tid & 63) == 0) wsum[tid >> 6] = ls;
  __syncthreads();
  if (tid == 0) lossp[lossbase + blockIdx.x] = wsum[0] + wsum[1] + wsum[2] + wsum[3];
}

__global__ void k_loss_final(const float* __restrict__ lossp, float* __restrict__ out) {
  if (threadIdx.x == 0 && blockIdx.x == 0) {
    float s = 0.f;
    for (int i = 0; i < 256; ++i) s += lossp[i];
    float L = s * (1.f / 4194304.f);
    out[R_RECON + 0] = L;
    out[R_RECON + 1] = L;
  }
}

extern "C" void kernel_launch(void* const* d_in, const int* in_sizes, int n_in,
                              void* d_out, int out_size, void* d_ws, size_t ws_size,
                              hipStream_t stream)
{
  float* out = (float*)d_out;          // fp32 output (established R8-R10)

  float* F = (float*)d_ws;
  float* LOSSP = F;
  int* FLAG = (int*)(F + 256);
  float* VQD = F + 272;
  float* VQI = VQD + 262144;
  float* A = VQI + 262144;

  int Bc = 64;
  while (Bc > 1 && 4ull * (272ull + 524288ull + (size_t)Bc * 393216ull) > ws_size) Bc >>= 1;
  float* H1 = A;
  float* H2 = A + (size_t)Bc * 262144;
  float* H3 = A;
  float* T  = A + (size_t)Bc * 131072;
  float* Z  = A + (size_t)Bc * 163840;
  float* D1 = H2;
  float* D2 = A;

  const void* patch = d_in[0];
  const void* ew1 = d_in[1];  const void* eb1 = d_in[2];
  const void* ew2 = d_in[3];  const void* eb2 = d_in[4];
  const void* ew3 = d_in[5];  const void* eb3 = d_in[6];
  const void* er1a = d_in[7]; const void* er1b = d_in[8];
  const void* er2a = d_in[9]; const void* er2b = d_in[10];
  const void* pqw = d_in[11]; const void* pqb = d_in[12];
  const void* emb = d_in[13];
  const void* dw1 = d_in[14]; const void* db1 = d_in[15];
  const void* dr1a = d_in[16]; const void* dr1b = d_in[17];
  const void* dr2a = d_in[18]; const void* dr2b = d_in[19];
  const void* dw2 = d_in[20]; const void* db2 = d_in[21];
  const void* dw3 = d_in[22]; const void* db3 = d_in[23];

  k_detect<<<1, 256, 0, stream>>>((const u16*)patch, FLAG);

  int NC = 64 / Bc;
  for (int c = 0; c < NC; ++c) {
    int b0 = c * Bc;

    // ---- encoder ----
    k_enc1<<<Bc * 128, 256, 0, stream>>>(patch, ew1, eb1, H1, FLAG, b0);
    k_enc2<<<Bc * 32, 256, 0, stream>>>(H1, ew2, eb2, H2, FLAG);
    k_conv3x3_v4<false, false, false, true><<<Bc * 32, 256, 0, stream>>>(H2, ew3, eb3, H3, FLAG, 128, 128);
    k_conv3x3_v4<true, false, true, false><<<Bc * 8, 256, 0, stream>>>(H3, er1a, nullptr, T, FLAG, 128, 32);
    k_conv1x1_t4<true, false, false><<<Bc * 32, 256, 0, stream>>>(T, er1b, nullptr, H3, FLAG, 32, 128);
    k_conv3x3_v4<true, false, true, false><<<Bc * 8, 256, 0, stream>>>(H3, er2a, nullptr, T, FLAG, 128, 32);
    k_conv1x1_t4<true, false, true><<<Bc * 32, 256, 0, stream>>>(T, er2b, nullptr, H3, FLAG, 32, 128);
    k_conv1x1_t4<false, true, false><<<Bc * 16, 256, 0, stream>>>(H3, pqw, pqb, Z, FLAG, 128, 64);

    // ---- VQ ----
    k_vq1<<<Bc * 16, 256, 0, stream>>>(Z, emb, FLAG, VQD, VQI);
    k_vq2<<<Bc * 4, 256, 0, stream>>>(Z, emb, FLAG, VQD, VQI, Z,
                                      out + R_RECON + 2 + (size_t)b0 * 1024, LOSSP, b0 * 4);

    // ---- decoder ----
    k_conv3x3_v4<false, true, false, true><<<Bc * 32, 256, 0, stream>>>(Z, dw1, db1, D1, FLAG, 64, 128);
    k_conv3x3_v4<true, false, true, false><<<Bc * 8, 256, 0, stream>>>(D1, dr1a, nullptr, T, FLAG, 128, 32);
    k_conv1x1_t4<true, false, false><<<Bc * 32, 256, 0, stream>>>(T, dr1b, nullptr, D1, FLAG, 32, 128);
    k_conv3x3_v4<true, false, true, false><<<Bc * 8, 256, 0, stream>>>(D1, dr2a, nullptr, T, FLAG, 128, 32);
    k_conv1x1_t4<true, false, true><<<Bc * 32, 256, 0, stream>>>(T, dr2b, nullptr, D1, FLAG, 32, 128);
    k_convT_up1<<<Bc * 16, 256, 0, stream>>>(D1, dw2, db2, D2, FLAG);
    k_convT_up2<<<Bc * 8, 256, 0, stream>>>(D2, dw3, db3, out + (size_t)b0 * 49152, FLAG);
  }

  k_loss_final<<<1, 64, 0, stream>>>(LOSSP, out);
}

// Round 23
// 2062.338 us; speedup vs baseline: 1.0525x; 1.0321x over previous
//
#include <hip/hip_runtime.h>
#include <hip/hip_bf16.h>

typedef __hip_bfloat16 bf16;
typedef unsigned short u16;

#define R_RECON 3145728
#define N_IDX   65536

__device__ __forceinline__ float ldg_in(const void* p, int i, int fl) {
  return fl ? ((const float*)p)[i] : __bfloat162float(((const bf16*)p)[i]);
}
__device__ __forceinline__ float cvt(float v) { return v; }
__device__ __forceinline__ float cvt(bf16 v) { return __bfloat162float(v); }

__global__ __launch_bounds__(256) void k_detect(const u16* __restrict__ p, int* __restrict__ flag) {
  __shared__ int s;
  if (threadIdx.x == 0) s = 0;
  __syncthreads();
  for (int i = threadIdx.x; i < 4096; i += 256) {
    float f = __uint_as_float(((unsigned)p[i]) << 16);
    if (!(fabsf(f) < 16384.f)) atomicOr(&s, 1);
  }
  __syncthreads();
  if (threadIdx.x == 0) flag[0] = s;
}

// ---------------- enc1: s2 k4 p1, 3ch 128x128 -> 64ch 64x64; 2 co/thread, 4-wide ox ----
template<typename T>
__device__ __forceinline__ void enc1_loop(
    const T* __restrict__ ip, int iy0, int cx0, const float* sW,
    float& a0, float& a1, float& a2, float& a3,
    float& b0, float& b1, float& b2, float& b3)
{
  #pragma unroll
  for (int ci = 0; ci < 3; ++ci) {
    const T* cp = ip + ci * 16384;
    #pragma unroll
    for (int ky = 0; ky < 4; ++ky) {
      int iy = iy0 + ky;
      if ((unsigned)iy < 128u) {
        const T* rp = cp + iy * 128;
        float x0 = (cx0 >= 0) ? cvt(rp[cx0]) : 0.f;
        float x1 = cvt(rp[cx0 + 1]), x2 = cvt(rp[cx0 + 2]);
        float x3 = cvt(rp[cx0 + 3]), x4 = cvt(rp[cx0 + 4]);
        float x5 = cvt(rp[cx0 + 5]), x6 = cvt(rp[cx0 + 6]);
        float x7 = cvt(rp[cx0 + 7]), x8 = cvt(rp[cx0 + 8]);
        float x9 = (cx0 + 9 < 128) ? cvt(rp[cx0 + 9]) : 0.f;
        const float* WA = sW + ci * 16 + ky * 4;
        float wa0 = WA[0], wa1 = WA[1], wa2 = WA[2], wa3 = WA[3];
        a0 = fmaf(x0, wa0, fmaf(x1, wa1, fmaf(x2, wa2, fmaf(x3, wa3, a0))));
        a1 = fmaf(x2, wa0, fmaf(x3, wa1, fmaf(x4, wa2, fmaf(x5, wa3, a1))));
        a2 = fmaf(x4, wa0, fmaf(x5, wa1, fmaf(x6, wa2, fmaf(x7, wa3, a2))));
        a3 = fmaf(x6, wa0, fmaf(x7, wa1, fmaf(x8, wa2, fmaf(x9, wa3, a3))));
        const float* WB = WA + 48;
        float wb0 = WB[0], wb1 = WB[1], wb2 = WB[2], wb3 = WB[3];
        b0 = fmaf(x0, wb0, fmaf(x1, wb1, fmaf(x2, wb2, fmaf(x3, wb3, b0))));
        b1 = fmaf(x2, wb0, fmaf(x3, wb1, fmaf(x4, wb2, fmaf(x5, wb3, b1))));
        b2 = fmaf(x4, wb0, fmaf(x5, wb1, fmaf(x6, wb2, fmaf(x7, wb3, b2))));
        b3 = fmaf(x6, wb0, fmaf(x7, wb1, fmaf(x8, wb2, fmaf(x9, wb3, b3))));
      }
    }
  }
}

__global__ __launch_bounds__(256) void k_enc1(
    const void* __restrict__ patch, const void* __restrict__ w,
    const void* __restrict__ bias, float* __restrict__ out,
    const int* __restrict__ flag, int n0)
{
  __shared__ float sW[96];
  __shared__ float sB[2];
  int fl = flag[0];
  int bid = blockIdx.x;
  int rg = bid & 3; int t = bid >> 2;
  int cp = t & 31;  int n = t >> 5;
  int co0 = cp * 2;
  int tid = threadIdx.x;
  if (tid < 96) sW[tid] = ldg_in(w, co0 * 48 + tid, fl);
  if (tid < 2)  sB[tid] = ldg_in(bias, co0 + tid, fl);
  __syncthreads();
  int ty = tid >> 4, txq = tid & 15;
  int oy = rg * 16 + ty;
  int ox0 = txq * 4;
  int iy0 = 2 * oy - 1, cx0 = 2 * ox0 - 1;
  float bv0 = sB[0], bv1 = sB[1];
  float a0 = bv0, a1 = bv0, a2 = bv0, a3 = bv0;
  float b0 = bv1, b1 = bv1, b2 = bv1, b3 = bv1;
  size_t ibase = (size_t)(n0 + n) * 49152;
  if (fl) enc1_loop((const float*)patch + ibase, iy0, cx0, sW, a0, a1, a2, a3, b0, b1, b2, b3);
  else    enc1_loop((const bf16*)patch + ibase, iy0, cx0, sW, a0, a1, a2, a3, b0, b1, b2, b3);
  float* op = out + (size_t)(n * 64 + co0) * 4096 + oy * 64 + ox0;
  op[0] = fmaxf(a0, 0.f); op[1] = fmaxf(a1, 0.f);
  op[2] = fmaxf(a2, 0.f); op[3] = fmaxf(a3, 0.f);
  op += 4096;
  op[0] = fmaxf(b0, 0.f); op[1] = fmaxf(b1, 0.f);
  op[2] = fmaxf(b2, 0.f); op[3] = fmaxf(b3, 0.f);
}

// ---------------- enc2 v3: s2 k4, 64ch 64x64 -> 128ch 32x32; 8 co/thread ----------------
// Weights staged PER-CI (128 floats) inside the plane-staging window -> no 32KB sW,
// LDS ~17.5KB, 4 blocks/CU. Per ci: 40 window reads feed 512 FMA (was 256).
// Per-accumulator chain order identical (ky asc, 4-term) -> bit-identical output.
#define E2_CO(PX, CL) { \
  float4 wv = *(const float4*)(sWc + (CL) * 16 + ky * 4); \
  PX##0 = fmaf(x0, wv.x, fmaf(x1, wv.y, fmaf(x2, wv.z, fmaf(x3, wv.w, PX##0)))); \
  PX##1 = fmaf(x2, wv.x, fmaf(x3, wv.y, fmaf(x4, wv.z, fmaf(x5, wv.w, PX##1)))); \
  PX##2 = fmaf(x4, wv.x, fmaf(x5, wv.y, fmaf(x6, wv.z, fmaf(x7, wv.w, PX##2)))); \
  PX##3 = fmaf(x6, wv.x, fmaf(x7, wv.y, fmaf(x8, wv.z, fmaf(x9, wv.w, PX##3)))); }

#define E2_ST(PX, OP) \
  (OP)[0] = fmaxf(PX##0, 0.f); (OP)[1] = fmaxf(PX##1, 0.f); \
  (OP)[2] = fmaxf(PX##2, 0.f); (OP)[3] = fmaxf(PX##3, 0.f);

__global__ __launch_bounds__(256) void k_enc2(
    const float* __restrict__ in, const void* __restrict__ w,
    const void* __restrict__ bias, float* __restrict__ out,
    const int* __restrict__ flag)
{
  const int Cin = 64, Cout = 128;
  const int P = 65;
  __shared__ float sIn[64 * P + 2];
  __shared__ __align__(16) float sWc[128];   // current-ci weights: 8 co x 16
  int fl = flag[0];
  int bid = blockIdx.x;
  int cp = bid & 15, n = bid >> 4;           // 16 co-octets
  int co0 = cp * 8;
  int tid = threadIdx.x;
  int oy = tid >> 3, ox0 = (tid & 7) << 2;
  float A0,A1,A2,A3, B0,B1,B2,B3, C0,C1,C2,C3, D0,D1,D2,D3;
  float E0,E1,E2,E3, F0,F1,F2,F3, G0,G1,G2,G3, H0,H1,H2,H3;
  {
    float bv;
    bv = ldg_in(bias, co0 + 0, fl); A0=bv; A1=bv; A2=bv; A3=bv;
    bv = ldg_in(bias, co0 + 1, fl); B0=bv; B1=bv; B2=bv; B3=bv;
    bv = ldg_in(bias, co0 + 2, fl); C0=bv; C1=bv; C2=bv; C3=bv;
    bv = ldg_in(bias, co0 + 3, fl); D0=bv; D1=bv; D2=bv; D3=bv;
    bv = ldg_in(bias, co0 + 4, fl); E0=bv; E1=bv; E2=bv; E3=bv;
    bv = ldg_in(bias, co0 + 5, fl); F0=bv; F1=bv; F2=bv; F3=bv;
    bv = ldg_in(bias, co0 + 6, fl); G0=bv; G1=bv; G2=bv; G3=bv;
    bv = ldg_in(bias, co0 + 7, fl); H0=bv; H1=bv; H2=bv; H3=bv;
  }
  int ry0 = 2 * oy - 1;
  int cx0 = 2 * ox0 - 1;
  const float* ip = in + (size_t)n * Cin * 4096;
  for (int ci = 0; ci < Cin; ++ci) {
    __syncthreads();                         // prior reads done before overwrite
    {
      const float4* g4 = (const float4*)(ip + ci * 4096);
      #pragma unroll
      for (int j = 0; j < 4; ++j) {
        int i4 = tid + j * 256;
        float4 v = g4[i4];
        int flat = i4 * 4;
        int iy = flat >> 6, ix = flat & 63;
        float* dst = sIn + iy * P + ((iy >> 3) & 1) + ix;
        dst[0] = v.x; dst[1] = v.y; dst[2] = v.z; dst[3] = v.w;
      }
      if (tid < 32) {                        // stage this ci's 8x16 weights
        int cl = tid >> 2, k4 = (tid & 3) * 4;
        int src = (co0 + cl) * 1024 + ci * 16 + k4;
        sWc[cl * 16 + k4 + 0] = ldg_in(w, src + 0, fl);
        sWc[cl * 16 + k4 + 1] = ldg_in(w, src + 1, fl);
        sWc[cl * 16 + k4 + 2] = ldg_in(w, src + 2, fl);
        sWc[cl * 16 + k4 + 3] = ldg_in(w, src + 3, fl);
      }
    }
    __syncthreads();
    #pragma unroll
    for (int ky = 0; ky < 4; ++ky) {
      int iy = ry0 + ky;
      if ((unsigned)iy < 64u) {
        const float* rp = sIn + iy * P + ((iy >> 3) & 1);
        float x0 = (cx0 >= 0) ? rp[cx0] : 0.f;
        float x1 = rp[cx0 + 1], x2 = rp[cx0 + 2], x3 = rp[cx0 + 3], x4 = rp[cx0 + 4];
        float x5 = rp[cx0 + 5], x6 = rp[cx0 + 6], x7 = rp[cx0 + 7], x8 = rp[cx0 + 8];
        float x9 = (cx0 + 9 < 64) ? rp[cx0 + 9] : 0.f;
        E2_CO(A, 0) E2_CO(B, 1) E2_CO(C, 2) E2_CO(D, 3)
        E2_CO(E, 4) E2_CO(F, 5) E2_CO(G, 6) E2_CO(H, 7)
      }
    }
  }
  float* op = out + (size_t)(n * Cout + co0) * 1024 + oy * 32 + ox0;
  E2_ST(A, op) op += 1024;
  E2_ST(B, op) op += 1024;
  E2_ST(C, op) op += 1024;
  E2_ST(D, op) op += 1024;
  E2_ST(E, op) op += 1024;
  E2_ST(F, op) op += 1024;
  E2_ST(G, op) op += 1024;
  E2_ST(H, op)
}

// ---- 3x3 conv s1 p1 @32x32 v4: 1 row x 8 px per thread, 4 co/block, 2 co/thread ----
#define LOAD10(RP) \
  x0 = (ox0 > 0) ? (RP)[ox0 - 1] : 0.f; \
  x1 = (RP)[ox0];     x2 = (RP)[ox0 + 1]; x3 = (RP)[ox0 + 2]; x4 = (RP)[ox0 + 3]; \
  x5 = (RP)[ox0 + 4]; x6 = (RP)[ox0 + 5]; x7 = (RP)[ox0 + 6]; x8 = (RP)[ox0 + 7]; \
  x9 = (ox0 < 24) ? (RP)[ox0 + 8] : 0.f; \
  if (IN_RELU) { \
    x0 = fmaxf(x0, 0.f); x1 = fmaxf(x1, 0.f); x2 = fmaxf(x2, 0.f); x3 = fmaxf(x3, 0.f); \
    x4 = fmaxf(x4, 0.f); x5 = fmaxf(x5, 0.f); x6 = fmaxf(x6, 0.f); x7 = fmaxf(x7, 0.f); \
    x8 = fmaxf(x8, 0.f); x9 = fmaxf(x9, 0.f); \
  }

#define C8(PX, W0, W1, W2) \
  PX##0 = fmaf(x0, W0, fmaf(x1, W1, fmaf(x2, W2, PX##0))); \
  PX##1 = fmaf(x1, W0, fmaf(x2, W1, fmaf(x3, W2, PX##1))); \
  PX##2 = fmaf(x2, W0, fmaf(x3, W1, fmaf(x4, W2, PX##2))); \
  PX##3 = fmaf(x3, W0, fmaf(x4, W1, fmaf(x5, W2, PX##3))); \
  PX##4 = fmaf(x4, W0, fmaf(x5, W1, fmaf(x6, W2, PX##4))); \
  PX##5 = fmaf(x5, W0, fmaf(x6, W1, fmaf(x7, W2, PX##5))); \
  PX##6 = fmaf(x6, W0, fmaf(x7, W1, fmaf(x8, W2, PX##6))); \
  PX##7 = fmaf(x7, W0, fmaf(x8, W1, fmaf(x9, W2, PX##7)));

#define ROW8_AB(KY) \
  C8(A, wa[3*KY], wa[3*KY+1], wa[3*KY+2]) \
  C8(B, wb[3*KY], wb[3*KY+1], wb[3*KY+2])

template<bool IN_RELU, bool TRANS_W, bool OUT_RELU, bool HAS_BIAS>
__global__ __launch_bounds__(256) void k_conv3x3_v4(
    const float* __restrict__ in, const void* __restrict__ w,
    const void* __restrict__ bias, float* __restrict__ out,
    const int* __restrict__ flag, int Cin, int Cout)
{
  const int HW = 1024;
  const int PP = 33;
  const int PLANE = 32 * PP;
  __shared__ float sW[4608];
  __shared__ float sIn[2 * 1056];
  int fl = flag[0];
  int nq = Cout >> 2;
  int bid = blockIdx.x;
  int qc = bid % nq, n = bid / nq;
  int co0 = qc * 4;
  int tid = threadIdx.x;
  int tot = 4 * Cin * 9;
  for (int i = tid; i < tot; i += 256) {
    int cl = i / (Cin * 9), rem = i % (Cin * 9);
    int ci = rem / 9, k = rem % 9;
    int src = TRANS_W ? ((ci * Cout + co0 + cl) * 9 + (8 - k))
                      : (((co0 + cl) * Cin + ci) * 9 + k);
    sW[i] = ldg_in(w, src, fl);
  }
  int cp = tid >> 7;
  int tt = tid & 127;
  int ty = tt >> 2;
  int tx = tt & 3;
  int ox0 = tx * 8;
  int coA = co0 + cp * 2;
  const float* WA = sW + (cp * 2) * Cin * 9;
  const float* WB = WA + Cin * 9;
  float bvA = HAS_BIAS ? ldg_in(bias, coA, fl) : 0.f;
  float bvB = HAS_BIAS ? ldg_in(bias, coA + 1, fl) : 0.f;
  float A0=bvA,A1=bvA,A2=bvA,A3=bvA,A4=bvA,A5=bvA,A6=bvA,A7=bvA;
  float B0=bvB,B1=bvB,B2=bvB,B3=bvB,B4=bvB,B5=bvB,B6=bvB,B7=bvB;
  const float* ip = in + (size_t)n * Cin * HW;
  for (int cb = 0; cb < Cin; cb += 2) {
    __syncthreads();
    {
      const float4* g4 = (const float4*)(ip + cb * HW);
      #pragma unroll
      for (int j = 0; j < 2; ++j) {
        int i4 = tid + j * 256;
        float4 v = g4[i4];
        int flat = i4 * 4;
        int pl = flat >> 10, rem = flat & 1023;
        float* dst = sIn + pl * PLANE + (rem >> 5) * PP + (rem & 31);
        dst[0] = v.x; dst[1] = v.y; dst[2] = v.z; dst[3] = v.w;
      }
    }
    __syncthreads();
    #pragma unroll
    for (int u = 0; u < 2; ++u) {
      int ci = cb + u;
      const float* sP = sIn + u * PLANE;
      const float* wa = WA + ci * 9;
      const float* wb = WB + ci * 9;
      float x0, x1, x2, x3, x4, x5, x6, x7, x8, x9;
      if (ty > 0) {
        LOAD10(sP + (ty - 1) * PP)
        ROW8_AB(0)
      }
      {
        LOAD10(sP + ty * PP)
        ROW8_AB(1)
      }
      if (ty < 31) {
        LOAD10(sP + (ty + 1) * PP)
        ROW8_AB(2)
      }
    }
  }
  float* op = out + (size_t)(n * Cout + coA) * HW + ty * 32 + ox0;
  if (OUT_RELU) {
    op[0] = fmaxf(A0, 0.f); op[1] = fmaxf(A1, 0.f); op[2] = fmaxf(A2, 0.f); op[3] = fmaxf(A3, 0.f);
    op[4] = fmaxf(A4, 0.f); op[5] = fmaxf(A5, 0.f); op[6] = fmaxf(A6, 0.f); op[7] = fmaxf(A7, 0.f);
    op += HW;
    op[0] = fmaxf(B0, 0.f); op[1] = fmaxf(B1, 0.f); op[2] = fmaxf(B2, 0.f); op[3] = fmaxf(B3, 0.f);
    op[4] = fmaxf(B4, 0.f); op[5] = fmaxf(B5, 0.f); op[6] = fmaxf(B6, 0.f); op[7] = fmaxf(B7, 0.f);
  } else {
    op[0] = A0; op[1] = A1; op[2] = A2; op[3] = A3;
    op[4] = A4; op[5] = A5; op[6] = A6; op[7] = A7;
    op += HW;
    op[0] = B0; op[1] = B1; op[2] = B2; op[3] = B3;
    op[4] = B4; op[5] = B5; op[6] = B6; op[7] = B7;
  }
}

// ---------------- 1x1 conv @32x32: 4co x 4p register tile ----------------
template<bool ACCUM, bool HAS_BIAS, bool OUT_RELU>
__global__ __launch_bounds__(256) void k_conv1x1_t4(
    const float* __restrict__ in, const void* __restrict__ w,
    const void* __restrict__ bias, float* __restrict__ out,
    const int* __restrict__ flag, int Cin, int Cout)
{
  const int HW = 1024;
  __shared__ float sW[512];
  int fl = flag[0];
  int nq = Cout >> 2;
  int bid = blockIdx.x;
  int qc = bid % nq, n = bid / nq;
  int co0 = qc * 4;
  int tid = threadIdx.x;
  for (int i = tid; i < 4 * Cin; i += 256)
    sW[i] = ldg_in(w, co0 * Cin + i, fl);
  __syncthreads();
  float acc[4][4];
  #pragma unroll
  for (int c = 0; c < 4; ++c) {
    float bv = HAS_BIAS ? ldg_in(bias, co0 + c, fl) : 0.f;
    #pragma unroll
    for (int k = 0; k < 4; ++k) acc[c][k] = bv;
  }
  const float* ip = in + (size_t)n * Cin * HW + tid;
  for (int ci = 0; ci < Cin; ++ci) {
    const float* p = ip + ci * HW;
    float x0 = p[0], x1 = p[256], x2 = p[512], x3 = p[768];
    #pragma unroll
    for (int c = 0; c < 4; ++c) {
      float wv = sW[c * Cin + ci];
      acc[c][0] = fmaf(wv, x0, acc[c][0]);
      acc[c][1] = fmaf(wv, x1, acc[c][1]);
      acc[c][2] = fmaf(wv, x2, acc[c][2]);
      acc[c][3] = fmaf(wv, x3, acc[c][3]);
    }
  }
  #pragma unroll
  for (int c = 0; c < 4; ++c) {
    float* op = out + (size_t)(n * Cout + co0 + c) * HW + tid;
    #pragma unroll
    for (int k = 0; k < 4; ++k) {
      float v = acc[c][k];
      if (ACCUM) v += op[k * 256];
      if (OUT_RELU) v = fmaxf(v, 0.f);
      op[k * 256] = v;
    }
  }
}

// ---- ConvTranspose s2 k4 p1 parity-quad macros ----
#define LOADW16V(BASE) { \
  const float4* w4_ = (const float4*)(BASE); \
  float4 t0_ = w4_[0], t1_ = w4_[1], t2_ = w4_[2], t3_ = w4_[3]; \
  w00 = t0_.x; w01 = t0_.y; w02 = t0_.z; w03 = t0_.w; \
  w10 = t1_.x; w11 = t1_.y; w12 = t1_.z; w13 = t1_.w; \
  w20 = t2_.x; w21 = t2_.y; w22 = t2_.z; w23 = t2_.w; \
  w30 = t3_.x; w31 = t3_.y; w32 = t3_.z; w33 = t3_.w; }

#define CT_J(P00, P01, P10, P11, M0, M1, M2, C0, C1, C2, D0, D1, D2) \
  P00 = fmaf(w11, C1, fmaf(w13, C0, fmaf(w31, M1, fmaf(w33, M0, P00)))); \
  P01 = fmaf(w10, C2, fmaf(w12, C1, fmaf(w30, M2, fmaf(w32, M1, P01)))); \
  P10 = fmaf(w01, D1, fmaf(w03, D0, fmaf(w21, C1, fmaf(w23, C0, P10)))); \
  P11 = fmaf(w00, D2, fmaf(w02, D1, fmaf(w20, C2, fmaf(w22, C1, P11))));

#define DECL16(PX, BV) \
  float PX##A0=BV, PX##A1=BV, PX##A2=BV, PX##A3=BV, \
        PX##B0=BV, PX##B1=BV, PX##B2=BV, PX##B3=BV, \
        PX##C0=BV, PX##C1=BV, PX##C2=BV, PX##C3=BV, \
        PX##D0=BV, PX##D1=BV, PX##D2=BV, PX##D3=BV;

#define CT_CO(PX) \
  CT_J(PX##A0, PX##B0, PX##C0, PX##D0, m0, m1, m2, c0, c1, c2, d0, d1, d2) \
  CT_J(PX##A1, PX##B1, PX##C1, PX##D1, m1, m2, m3, c1, c2, c3, d1, d2, d3) \
  CT_J(PX##A2, PX##B2, PX##C2, PX##D2, m2, m3, m4, c2, c3, c4, d2, d3, d4) \
  CT_J(PX##A3, PX##B3, PX##C3, PX##D3, m3, m4, m5, c3, c4, c5, d3, d4, d5)

#define CT_STORE(PX, PTR, HO) \
  (PTR)[0] = fmaxf(PX##A0, 0.f); (PTR)[1] = fmaxf(PX##B0, 0.f); \
  (PTR)[2] = fmaxf(PX##A1, 0.f); (PTR)[3] = fmaxf(PX##B1, 0.f); \
  (PTR)[4] = fmaxf(PX##A2, 0.f); (PTR)[5] = fmaxf(PX##B2, 0.f); \
  (PTR)[6] = fmaxf(PX##A3, 0.f); (PTR)[7] = fmaxf(PX##B3, 0.f); \
  (PTR)[HO]     = fmaxf(PX##C0, 0.f); (PTR)[HO + 1] = fmaxf(PX##D0, 0.f); \
  (PTR)[HO + 2] = fmaxf(PX##C1, 0.f); (PTR)[HO + 3] = fmaxf(PX##D1, 0.f); \
  (PTR)[HO + 4] = fmaxf(PX##C2, 0.f); (PTR)[HO + 5] = fmaxf(PX##D2, 0.f); \
  (PTR)[HO + 6] = fmaxf(PX##C3, 0.f); (PTR)[HO + 7] = fmaxf(PX##D3, 0.f);

// ---------------- up1: convT s2 k4, 128ch 32x32 -> 64ch 64x64, 4 co/thread, staged input ----
__global__ __launch_bounds__(256) void k_convT_up1(
    const float* __restrict__ in, const void* __restrict__ w,
    const void* __restrict__ bias, float* __restrict__ out,
    const int* __restrict__ flag)
{
  const int Cin = 128, Cout = 64;
  const int PP = 33;
  __shared__ __align__(16) float sW[8192];
  __shared__ float sIn[32 * PP];
  int fl = flag[0];
  int bid = blockIdx.x;
  int cp = bid & 15, n = bid >> 4;
  int co0 = cp * 4;
  int tid = threadIdx.x;
  for (int i = tid; i < 8192; i += 256) {
    int cl = i >> 11, rem = i & 2047;
    int ci = rem >> 4, k = rem & 15;
    sW[i] = ldg_in(w, (ci * Cout + co0 + cl) * 16 + k, fl);
  }
  int qa = tid >> 3;
  int qb0 = (tid & 7) * 4;
  float bv0 = ldg_in(bias, co0, fl), bv1 = ldg_in(bias, co0 + 1, fl);
  float bv2 = ldg_in(bias, co0 + 2, fl), bv3 = ldg_in(bias, co0 + 3, fl);
  DECL16(u, bv0) DECL16(v, bv1) DECL16(y, bv2) DECL16(z, bv3)
  const float* ip = in + (size_t)n * Cin * 1024;
  bool vm = qa >= 1, vd = qa + 1 < 32;
  bool vl = qb0 > 0, vr = qb0 < 28;
  for (int ci = 0; ci < Cin; ++ci) {
    __syncthreads();
    {
      float4 g = ((const float4*)(ip + ci * 1024))[tid];
      float* dst = sIn + (tid >> 3) * PP + (tid & 7) * 4;
      dst[0] = g.x; dst[1] = g.y; dst[2] = g.z; dst[3] = g.w;
    }
    __syncthreads();
    const float* rm = sIn + (qa - 1) * PP;
    const float* rc = sIn + qa * PP;
    const float* rd = sIn + (qa + 1) * PP;
    float m0 = (vm && vl) ? rm[qb0 - 1] : 0.f;
    float m1 = vm ? rm[qb0] : 0.f, m2 = vm ? rm[qb0 + 1] : 0.f;
    float m3 = vm ? rm[qb0 + 2] : 0.f, m4 = vm ? rm[qb0 + 3] : 0.f;
    float m5 = (vm && vr) ? rm[qb0 + 4] : 0.f;
    float c0 = vl ? rc[qb0 - 1] : 0.f;
    float c1 = rc[qb0], c2 = rc[qb0 + 1], c3 = rc[qb0 + 2], c4 = rc[qb0 + 3];
    float c5 = vr ? rc[qb0 + 4] : 0.f;
    float d0 = (vd && vl) ? rd[qb0 - 1] : 0.f;
    float d1 = vd ? rd[qb0] : 0.f, d2 = vd ? rd[qb0 + 1] : 0.f;
    float d3 = vd ? rd[qb0 + 2] : 0.f, d4 = vd ? rd[qb0 + 3] : 0.f;
    float d5 = (vd && vr) ? rd[qb0 + 4] : 0.f;
    float w00, w01, w02, w03, w10, w11, w12, w13, w20, w21, w22, w23, w30, w31, w32, w33;
    { LOADW16V(sW + ci * 16)        CT_CO(u) }
    { LOADW16V(sW + 2048 + ci * 16) CT_CO(v) }
    { LOADW16V(sW + 4096 + ci * 16) CT_CO(y) }
    { LOADW16V(sW + 6144 + ci * 16) CT_CO(z) }
  }
  float* op = out + ((size_t)(n * Cout + co0) * 64 + 2 * qa) * 64 + 2 * qb0;
  CT_STORE(u, op, 64) op += (size_t)64 * 64;
  CT_STORE(v, op, 64) op += (size_t)64 * 64;
  CT_STORE(y, op, 64) op += (size_t)64 * 64;
  CT_STORE(z, op, 64)
}

// ---------------- up2: convT s2 k4, 64ch 64x64 -> 3ch 128x128, all 3 co/thread ----------------
__global__ __launch_bounds__(256) void k_convT_up2(
    const float* __restrict__ in, const void* __restrict__ w,
    const void* __restrict__ bias, float* __restrict__ out,
    const int* __restrict__ flag)
{
  const int Cin = 64;
  __shared__ __align__(16) float sW[3072];
  int fl = flag[0];
  int bid = blockIdx.x;
  int s = bid & 7, n = bid >> 3;
  int tid = threadIdx.x;
  for (int i = tid; i < 3072; i += 256)
    sW[i] = ldg_in(w, i, fl);
  __syncthreads();
  int qa = s * 8 + (tid >> 5);
  int qb0 = (tid & 31) * 2;
  float bp = ldg_in(bias, 0, fl), bq = ldg_in(bias, 1, fl), br = ldg_in(bias, 2, fl);
  float pA0 = bp, pA1 = bp, pB0 = bp, pB1 = bp, pC0 = bp, pC1 = bp, pD0 = bp, pD1 = bp;
  float qA0 = bq, qA1 = bq, qB0_ = bq, qB1 = bq, qC0 = bq, qC1 = bq, qD0 = bq, qD1 = bq;
  float rA0 = br, rA1 = br, rB0 = br, rB1 = br, rC0 = br, rC1 = br, rD0 = br, rD1 = br;
  const float* ip = in + (size_t)n * Cin * 4096;
  bool vm = qa >= 1, vd = qa + 1 < 64;
  bool vl = qb0 > 0, vr = qb0 < 62;
  for (int ci = 0; ci < Cin; ++ci) {
    const float* p = ip + ci * 4096;
    const float* rm = p + (qa - 1) * 64;
    const float* rc = p + qa * 64;
    const float* rd = p + (qa + 1) * 64;
    float m0 = (vm && vl) ? rm[qb0 - 1] : 0.f;
    float m1 = vm ? rm[qb0] : 0.f, m2 = vm ? rm[qb0 + 1] : 0.f;
    float m3 = (vm && vr) ? rm[qb0 + 2] : 0.f;
    float c0 = vl ? rc[qb0 - 1] : 0.f;
    float c1 = rc[qb0], c2 = rc[qb0 + 1];
    float c3 = vr ? rc[qb0 + 2] : 0.f;
    float d0 = (vd && vl) ? rd[qb0 - 1] : 0.f;
    float d1 = vd ? rd[qb0] : 0.f, d2 = vd ? rd[qb0 + 1] : 0.f;
    float d3 = (vd && vr) ? rd[qb0 + 2] : 0.f;
    float w00, w01, w02, w03, w10, w11, w12, w13, w20, w21, w22, w23, w30, w31, w32, w33;
    {
      LOADW16V(sW + ci * 48)
      CT_J(pA0, pB0, pC0, pD0, m0, m1, m2, c0, c1, c2, d0, d1, d2)
      CT_J(pA1, pB1, pC1, pD1, m1, m2, m3, c1, c2, c3, d1, d2, d3)
    }
    {
      LOADW16V(sW + ci * 48 + 16)
      CT_J(qA0, qB0_, qC0, qD0, m0, m1, m2, c0, c1, c2, d0, d1, d2)
      CT_J(qA1, qB1, qC1, qD1, m1, m2, m3, c1, c2, c3, d1, d2, d3)
    }
    {
      LOADW16V(sW + ci * 48 + 32)
      CT_J(rA0, rB0, rC0, rD0, m0, m1, m2, c0, c1, c2, d0, d1, d2)
      CT_J(rA1, rB1, rC1, rD1, m1, m2, m3, c1, c2, c3, d1, d2, d3)
    }
  }
  float* op = out + ((size_t)(n * 3 + 0) * 128 + 2 * qa) * 128 + 2 * qb0;
  op[0] = pA0; op[1] = pB0; op[2] = pA1; op[3] = pB1;
  op[128] = pC0; op[129] = pD0; op[130] = pC1; op[131] = pD1;
  op += (size_t)128 * 128;
  op[0] = qA0; op[1] = qB0_; op[2] = qA1; op[3] = qB1;
  op[128] = qC0; op[129] = qD0; op[130] = qC1; op[131] = qD1;
  op += (size_t)128 * 128;
  op[0] = rA0; op[1] = rB0; op[2] = rA1; op[3] = rB1;
  op[128] = rC0; op[129] = rD0; op[130] = rC1; op[131] = rD1;
}

// ---------------- VQ phase 1: per-chunk argmin (256 codebook rows per chunk) ----------------
__global__ __launch_bounds__(256) void k_vq1(
    const float* __restrict__ z, const void* __restrict__ emb,
    const int* __restrict__ flag, float* __restrict__ distb, float* __restrict__ idxb)
{
  const int PE = 65;
  __shared__ float sE[128 * PE];
  __shared__ float sEE[128];
  int fl = flag[0];
  int tid = threadIdx.x;
  int bid = blockIdx.x;
  int ch = bid & 3, vb = bid >> 2;
  int n = vb * 256 + tid;
  int nb = n >> 10, p = n & 1023;
  const float* zp = z + nb * 65536 + p;
  float zv[64];
  float zz = 0.f;
  #pragma unroll
  for (int d = 0; d < 64; ++d) { zv[d] = zp[d * 1024]; zz = fmaf(zv[d], zv[d], zz); }
  float best = 3.4e38f; int bidx = ch * 256;
  for (int kb = ch * 2; kb < ch * 2 + 2; ++kb) {
    __syncthreads();
    for (int i = tid; i < 8192; i += 256)
      sE[(i >> 6) * PE + (i & 63)] = ldg_in(emb, kb * 8192 + i, fl);
    __syncthreads();
    if (tid < 128) {
      const float* ep = sE + tid * PE;
      float s = 0.f;
      #pragma unroll
      for (int d = 0; d < 64; ++d) s = fmaf(ep[d], ep[d], s);
      sEE[tid] = s;
    }
    __syncthreads();
    for (int k = 0; k < 128; ++k) {
      const float* ep = sE + k * PE;
      float dot = 0.f;
      #pragma unroll
      for (int d = 0; d < 64; ++d) dot = fmaf(zv[d], ep[d], dot);
      float dist = zz + sEE[k] - 2.f * dot;
      if (dist < best) { best = dist; bidx = kb * 128 + k; }  // strict <: first min wins
    }
  }
  distb[ch * 65536 + n] = best;
  idxb[ch * 65536 + n] = (float)bidx;
}

// ---------------- VQ phase 2: combine chunks, gather zq, loss partials ----------------
__global__ __launch_bounds__(256) void k_vq2(
    const float* __restrict__ z, const void* __restrict__ emb,
    const int* __restrict__ flag, const float* __restrict__ distb,
    const float* __restrict__ idxb, float* __restrict__ zq,
    float* __restrict__ idx_out, float* __restrict__ lossp, int lossbase)
{
  __shared__ float wsum[4];
  int fl = flag[0];
  int tid = threadIdx.x;
  int n = blockIdx.x * 256 + tid;
  float best = distb[n];
  int bidx = (int)idxb[n];
  #pragma unroll
  for (int c = 1; c < 4; ++c) {
    float d = distb[c * 65536 + n];
    if (d < best) { best = d; bidx = (int)idxb[c * 65536 + n]; }  // earlier chunk wins ties
  }
  idx_out[n] = (float)bidx;
  int nb = n >> 10, p = n & 1023;
  const float* zp = z + nb * 65536 + p;
  float* qp = zq + nb * 65536 + p;
  float ls = 0.f;
  #pragma unroll
  for (int d = 0; d < 64; ++d) {
    float e = ldg_in(emb, bidx * 64 + d, fl);
    float zvd = zp[d * 1024];
    qp[d * 1024] = e;
    float df = e - zvd;
    ls = fmaf(df, df, ls);
  }
  #pragma unroll
  for (int off = 32; off > 0; off >>= 1) ls += __shfl_down(ls, off);
  if ((tid & 63) == 0) wsum[tid >> 6] = ls;
  __syncthreads();
  if (tid == 0) lossp[lossbase + blockIdx.x] = wsum[0] + wsum[1] + wsum[2] + wsum[3];
}

__global__ void k_loss_final(const float* __restrict__ lossp, float* __restrict__ out) {
  if (threadIdx.x == 0 && blockIdx.x == 0) {
    float s = 0.f;
    for (int i = 0; i < 256; ++i) s += lossp[i];
    float L = s * (1.f / 4194304.f);
    out[R_RECON + 0] = L;
    out[R_RECON + 1] = L;
  }
}

extern "C" void kernel_launch(void* const* d_in, const int* in_sizes, int n_in,
                              void* d_out, int out_size, void* d_ws, size_t ws_size,
                              hipStream_t stream)
{
  float* out = (float*)d_out;          // fp32 output (established R8-R10)

  float* F = (float*)d_ws;
  float* LOSSP = F;
  int* FLAG = (int*)(F + 256);
  float* VQD = F + 272;
  float* VQI = VQD + 262144;
  float* A = VQI + 262144;

  int Bc = 64;
  while (Bc > 1 && 4ull * (272ull + 524288ull + (size_t)Bc * 393216ull) > ws_size) Bc >>= 1;
  float* H1 = A;
  float* H2 = A + (size_t)Bc * 262144;
  float* H3 = A;
  float* T  = A + (size_t)Bc * 131072;
  float* Z  = A + (size_t)Bc * 163840;
  float* D1 = H2;
  float* D2 = A;

  const void* patch = d_in[0];
  const void* ew1 = d_in[1];  const void* eb1 = d_in[2];
  const void* ew2 = d_in[3];  const void* eb2 = d_in[4];
  const void* ew3 = d_in[5];  const void* eb3 = d_in[6];
  const void* er1a = d_in[7]; const void* er1b = d_in[8];
  const void* er2a = d_in[9]; const void* er2b = d_in[10];
  const void* pqw = d_in[11]; const void* pqb = d_in[12];
  const void* emb = d_in[13];
  const void* dw1 = d_in[14]; const void* db1 = d_in[15];
  const void* dr1a = d_in[16]; const void* dr1b = d_in[17];
  const void* dr2a = d_in[18]; const void* dr2b = d_in[19];
  const void* dw2 = d_in[20]; const void* db2 = d_in[21];
  const void* dw3 = d_in[22]; const void* db3 = d_in[23];

  k_detect<<<1, 256, 0, stream>>>((const u16*)patch, FLAG);

  int NC = 64 / Bc;
  for (int c = 0; c < NC; ++c) {
    int b0 = c * Bc;

    // ---- encoder ----
    k_enc1<<<Bc * 128, 256, 0, stream>>>(patch, ew1, eb1, H1, FLAG, b0);
    k_enc2<<<Bc * 16, 256, 0, stream>>>(H1, ew2, eb2, H2, FLAG);
    k_conv3x3_v4<false, false, false, true><<<Bc * 32, 256, 0, stream>>>(H2, ew3, eb3, H3, FLAG, 128, 128);
    k_conv3x3_v4<true, false, true, false><<<Bc * 8, 256, 0, stream>>>(H3, er1a, nullptr, T, FLAG, 128, 32);
    k_conv1x1_t4<true, false, false><<<Bc * 32, 256, 0, stream>>>(T, er1b, nullptr, H3, FLAG, 32, 128);
    k_conv3x3_v4<true, false, true, false><<<Bc * 8, 256, 0, stream>>>(H3, er2a, nullptr, T, FLAG, 128, 32);
    k_conv1x1_t4<true, false, true><<<Bc * 32, 256, 0, stream>>>(T, er2b, nullptr, H3, FLAG, 32, 128);
    k_conv1x1_t4<false, true, false><<<Bc * 16, 256, 0, stream>>>(H3, pqw, pqb, Z, FLAG, 128, 64);

    // ---- VQ ----
    k_vq1<<<Bc * 16, 256, 0, stream>>>(Z, emb, FLAG, VQD, VQI);
    k_vq2<<<Bc * 4, 256, 0, stream>>>(Z, emb, FLAG, VQD, VQI, Z,
                                      out + R_RECON + 2 + (size_t)b0 * 1024, LOSSP, b0 * 4);

    // ---- decoder ----
    k_conv3x3_v4<false, true, false, true><<<Bc * 32, 256, 0, stream>>>(Z, dw1, db1, D1, FLAG, 64, 128);
    k_conv3x3_v4<true, false, true, false><<<Bc * 8, 256, 0, stream>>>(D1, dr1a, nullptr, T, FLAG, 128, 32);
    k_conv1x1_t4<true, false, false><<<Bc * 32, 256, 0, stream>>>(T, dr1b, nullptr, D1, FLAG, 32, 128);
    k_conv3x3_v4<true, false, true, false><<<Bc * 8, 256, 0, stream>>>(D1, dr2a, nullptr, T, FLAG, 128, 32);
    k_conv1x1_t4<true, false, true><<<Bc * 32, 256, 0, stream>>>(T, dr2b, nullptr, D1, FLAG, 32, 128);
    k_convT_up1<<<Bc * 16, 256, 0, stream>>>(D1, dw2, db2, D2, FLAG);
    k_convT_up2<<<Bc * 8, 256, 0, stream>>>(D2, dw3, db3, out + (size_t)b0 * 49152, FLAG);
  }

  k_loss_final<<<1, 64, 0, stream>>>(LOSSP, out);
}

// Round 24
// 1951.072 us; speedup vs baseline: 1.1126x; 1.0570x over previous
//
#include <hip/hip_runtime.h>
#include <hip/hip_bf16.h>

typedef __hip_bfloat16 bf16;
typedef unsigned short u16;

#define R_RECON 3145728
#define N_IDX   65536

__device__ __forceinline__ float ldg_in(const void* p, int i, int fl) {
  return fl ? ((const float*)p)[i] : __bfloat162float(((const bf16*)p)[i]);
}
__device__ __forceinline__ float cvt(float v) { return v; }
__device__ __forceinline__ float cvt(bf16 v) { return __bfloat162float(v); }

__global__ __launch_bounds__(256) void k_detect(const u16* __restrict__ p, int* __restrict__ flag) {
  __shared__ int s;
  if (threadIdx.x == 0) s = 0;
  __syncthreads();
  for (int i = threadIdx.x; i < 4096; i += 256) {
    float f = __uint_as_float(((unsigned)p[i]) << 16);
    if (!(fabsf(f) < 16384.f)) atomicOr(&s, 1);
  }
  __syncthreads();
  if (threadIdx.x == 0) flag[0] = s;
}

// ---------------- enc1: s2 k4 p1, 3ch 128x128 -> 64ch 64x64; 2 co/thread, 4-wide ox ----
template<typename T>
__device__ __forceinline__ void enc1_loop(
    const T* __restrict__ ip, int iy0, int cx0, const float* sW,
    float& a0, float& a1, float& a2, float& a3,
    float& b0, float& b1, float& b2, float& b3)
{
  #pragma unroll
  for (int ci = 0; ci < 3; ++ci) {
    const T* cp = ip + ci * 16384;
    #pragma unroll
    for (int ky = 0; ky < 4; ++ky) {
      int iy = iy0 + ky;
      if ((unsigned)iy < 128u) {
        const T* rp = cp + iy * 128;
        float x0 = (cx0 >= 0) ? cvt(rp[cx0]) : 0.f;
        float x1 = cvt(rp[cx0 + 1]), x2 = cvt(rp[cx0 + 2]);
        float x3 = cvt(rp[cx0 + 3]), x4 = cvt(rp[cx0 + 4]);
        float x5 = cvt(rp[cx0 + 5]), x6 = cvt(rp[cx0 + 6]);
        float x7 = cvt(rp[cx0 + 7]), x8 = cvt(rp[cx0 + 8]);
        float x9 = (cx0 + 9 < 128) ? cvt(rp[cx0 + 9]) : 0.f;
        const float* WA = sW + ci * 16 + ky * 4;
        float wa0 = WA[0], wa1 = WA[1], wa2 = WA[2], wa3 = WA[3];
        a0 = fmaf(x0, wa0, fmaf(x1, wa1, fmaf(x2, wa2, fmaf(x3, wa3, a0))));
        a1 = fmaf(x2, wa0, fmaf(x3, wa1, fmaf(x4, wa2, fmaf(x5, wa3, a1))));
        a2 = fmaf(x4, wa0, fmaf(x5, wa1, fmaf(x6, wa2, fmaf(x7, wa3, a2))));
        a3 = fmaf(x6, wa0, fmaf(x7, wa1, fmaf(x8, wa2, fmaf(x9, wa3, a3))));
        const float* WB = WA + 48;
        float wb0 = WB[0], wb1 = WB[1], wb2 = WB[2], wb3 = WB[3];
        b0 = fmaf(x0, wb0, fmaf(x1, wb1, fmaf(x2, wb2, fmaf(x3, wb3, b0))));
        b1 = fmaf(x2, wb0, fmaf(x3, wb1, fmaf(x4, wb2, fmaf(x5, wb3, b1))));
        b2 = fmaf(x4, wb0, fmaf(x5, wb1, fmaf(x6, wb2, fmaf(x7, wb3, b2))));
        b3 = fmaf(x6, wb0, fmaf(x7, wb1, fmaf(x8, wb2, fmaf(x9, wb3, b3))));
      }
    }
  }
}

__global__ __launch_bounds__(256) void k_enc1(
    const void* __restrict__ patch, const void* __restrict__ w,
    const void* __restrict__ bias, float* __restrict__ out,
    const int* __restrict__ flag, int n0)
{
  __shared__ float sW[96];
  __shared__ float sB[2];
  int fl = flag[0];
  int bid = blockIdx.x;
  int rg = bid & 3; int t = bid >> 2;
  int cp = t & 31;  int n = t >> 5;
  int co0 = cp * 2;
  int tid = threadIdx.x;
  if (tid < 96) sW[tid] = ldg_in(w, co0 * 48 + tid, fl);
  if (tid < 2)  sB[tid] = ldg_in(bias, co0 + tid, fl);
  __syncthreads();
  int ty = tid >> 4, txq = tid & 15;
  int oy = rg * 16 + ty;
  int ox0 = txq * 4;
  int iy0 = 2 * oy - 1, cx0 = 2 * ox0 - 1;
  float bv0 = sB[0], bv1 = sB[1];
  float a0 = bv0, a1 = bv0, a2 = bv0, a3 = bv0;
  float b0 = bv1, b1 = bv1, b2 = bv1, b3 = bv1;
  size_t ibase = (size_t)(n0 + n) * 49152;
  if (fl) enc1_loop((const float*)patch + ibase, iy0, cx0, sW, a0, a1, a2, a3, b0, b1, b2, b3);
  else    enc1_loop((const bf16*)patch + ibase, iy0, cx0, sW, a0, a1, a2, a3, b0, b1, b2, b3);
  float* op = out + (size_t)(n * 64 + co0) * 4096 + oy * 64 + ox0;
  op[0] = fmaxf(a0, 0.f); op[1] = fmaxf(a1, 0.f);
  op[2] = fmaxf(a2, 0.f); op[3] = fmaxf(a3, 0.f);
  op += 4096;
  op[0] = fmaxf(b0, 0.f); op[1] = fmaxf(b1, 0.f);
  op[2] = fmaxf(b2, 0.f); op[3] = fmaxf(b3, 0.f);
}

// ---------------- enc2 v3: s2 k4, 64ch 64x64 -> 128ch 32x32; 8 co/thread ----------------
#define E2_CO(PX, CL) { \
  float4 wv = *(const float4*)(sWc + (CL) * 16 + ky * 4); \
  PX##0 = fmaf(x0, wv.x, fmaf(x1, wv.y, fmaf(x2, wv.z, fmaf(x3, wv.w, PX##0)))); \
  PX##1 = fmaf(x2, wv.x, fmaf(x3, wv.y, fmaf(x4, wv.z, fmaf(x5, wv.w, PX##1)))); \
  PX##2 = fmaf(x4, wv.x, fmaf(x5, wv.y, fmaf(x6, wv.z, fmaf(x7, wv.w, PX##2)))); \
  PX##3 = fmaf(x6, wv.x, fmaf(x7, wv.y, fmaf(x8, wv.z, fmaf(x9, wv.w, PX##3)))); }

#define E2_ST(PX, OP) \
  (OP)[0] = fmaxf(PX##0, 0.f); (OP)[1] = fmaxf(PX##1, 0.f); \
  (OP)[2] = fmaxf(PX##2, 0.f); (OP)[3] = fmaxf(PX##3, 0.f);

__global__ __launch_bounds__(256) void k_enc2(
    const float* __restrict__ in, const void* __restrict__ w,
    const void* __restrict__ bias, float* __restrict__ out,
    const int* __restrict__ flag)
{
  const int Cin = 64, Cout = 128;
  const int P = 65;
  __shared__ float sIn[64 * P + 2];
  __shared__ __align__(16) float sWc[128];
  int fl = flag[0];
  int bid = blockIdx.x;
  int cp = bid & 15, n = bid >> 4;
  int co0 = cp * 8;
  int tid = threadIdx.x;
  int oy = tid >> 3, ox0 = (tid & 7) << 2;
  float A0,A1,A2,A3, B0,B1,B2,B3, C0,C1,C2,C3, D0,D1,D2,D3;
  float E0,E1,E2,E3, F0,F1,F2,F3, G0,G1,G2,G3, H0,H1,H2,H3;
  {
    float bv;
    bv = ldg_in(bias, co0 + 0, fl); A0=bv; A1=bv; A2=bv; A3=bv;
    bv = ldg_in(bias, co0 + 1, fl); B0=bv; B1=bv; B2=bv; B3=bv;
    bv = ldg_in(bias, co0 + 2, fl); C0=bv; C1=bv; C2=bv; C3=bv;
    bv = ldg_in(bias, co0 + 3, fl); D0=bv; D1=bv; D2=bv; D3=bv;
    bv = ldg_in(bias, co0 + 4, fl); E0=bv; E1=bv; E2=bv; E3=bv;
    bv = ldg_in(bias, co0 + 5, fl); F0=bv; F1=bv; F2=bv; F3=bv;
    bv = ldg_in(bias, co0 + 6, fl); G0=bv; G1=bv; G2=bv; G3=bv;
    bv = ldg_in(bias, co0 + 7, fl); H0=bv; H1=bv; H2=bv; H3=bv;
  }
  int ry0 = 2 * oy - 1;
  int cx0 = 2 * ox0 - 1;
  const float* ip = in + (size_t)n * Cin * 4096;
  for (int ci = 0; ci < Cin; ++ci) {
    __syncthreads();
    {
      const float4* g4 = (const float4*)(ip + ci * 4096);
      #pragma unroll
      for (int j = 0; j < 4; ++j) {
        int i4 = tid + j * 256;
        float4 v = g4[i4];
        int flat = i4 * 4;
        int iy = flat >> 6, ix = flat & 63;
        float* dst = sIn + iy * P + ((iy >> 3) & 1) + ix;
        dst[0] = v.x; dst[1] = v.y; dst[2] = v.z; dst[3] = v.w;
      }
      if (tid < 32) {
        int cl = tid >> 2, k4 = (tid & 3) * 4;
        int src = (co0 + cl) * 1024 + ci * 16 + k4;
        sWc[cl * 16 + k4 + 0] = ldg_in(w, src + 0, fl);
        sWc[cl * 16 + k4 + 1] = ldg_in(w, src + 1, fl);
        sWc[cl * 16 + k4 + 2] = ldg_in(w, src + 2, fl);
        sWc[cl * 16 + k4 + 3] = ldg_in(w, src + 3, fl);
      }
    }
    __syncthreads();
    #pragma unroll
    for (int ky = 0; ky < 4; ++ky) {
      int iy = ry0 + ky;
      if ((unsigned)iy < 64u) {
        const float* rp = sIn + iy * P + ((iy >> 3) & 1);
        float x0 = (cx0 >= 0) ? rp[cx0] : 0.f;
        float x1 = rp[cx0 + 1], x2 = rp[cx0 + 2], x3 = rp[cx0 + 3], x4 = rp[cx0 + 4];
        float x5 = rp[cx0 + 5], x6 = rp[cx0 + 6], x7 = rp[cx0 + 7], x8 = rp[cx0 + 8];
        float x9 = (cx0 + 9 < 64) ? rp[cx0 + 9] : 0.f;
        E2_CO(A, 0) E2_CO(B, 1) E2_CO(C, 2) E2_CO(D, 3)
        E2_CO(E, 4) E2_CO(F, 5) E2_CO(G, 6) E2_CO(H, 7)
      }
    }
  }
  float* op = out + (size_t)(n * Cout + co0) * 1024 + oy * 32 + ox0;
  E2_ST(A, op) op += 1024;
  E2_ST(B, op) op += 1024;
  E2_ST(C, op) op += 1024;
  E2_ST(D, op) op += 1024;
  E2_ST(E, op) op += 1024;
  E2_ST(F, op) op += 1024;
  E2_ST(G, op) op += 1024;
  E2_ST(H, op)
}

// ---- 3x3 conv s1 p1 @32x32 v4: 1 row x 8 px per thread, 4 co/block, 2 co/thread ----
#define LOAD10(RP) \
  x0 = (ox0 > 0) ? (RP)[ox0 - 1] : 0.f; \
  x1 = (RP)[ox0];     x2 = (RP)[ox0 + 1]; x3 = (RP)[ox0 + 2]; x4 = (RP)[ox0 + 3]; \
  x5 = (RP)[ox0 + 4]; x6 = (RP)[ox0 + 5]; x7 = (RP)[ox0 + 6]; x8 = (RP)[ox0 + 7]; \
  x9 = (ox0 < 24) ? (RP)[ox0 + 8] : 0.f; \
  if (IN_RELU) { \
    x0 = fmaxf(x0, 0.f); x1 = fmaxf(x1, 0.f); x2 = fmaxf(x2, 0.f); x3 = fmaxf(x3, 0.f); \
    x4 = fmaxf(x4, 0.f); x5 = fmaxf(x5, 0.f); x6 = fmaxf(x6, 0.f); x7 = fmaxf(x7, 0.f); \
    x8 = fmaxf(x8, 0.f); x9 = fmaxf(x9, 0.f); \
  }

#define C8(PX, W0, W1, W2) \
  PX##0 = fmaf(x0, W0, fmaf(x1, W1, fmaf(x2, W2, PX##0))); \
  PX##1 = fmaf(x1, W0, fmaf(x2, W1, fmaf(x3, W2, PX##1))); \
  PX##2 = fmaf(x2, W0, fmaf(x3, W1, fmaf(x4, W2, PX##2))); \
  PX##3 = fmaf(x3, W0, fmaf(x4, W1, fmaf(x5, W2, PX##3))); \
  PX##4 = fmaf(x4, W0, fmaf(x5, W1, fmaf(x6, W2, PX##4))); \
  PX##5 = fmaf(x5, W0, fmaf(x6, W1, fmaf(x7, W2, PX##5))); \
  PX##6 = fmaf(x6, W0, fmaf(x7, W1, fmaf(x8, W2, PX##6))); \
  PX##7 = fmaf(x7, W0, fmaf(x8, W1, fmaf(x9, W2, PX##7)));

#define ROW8_AB(KY) \
  C8(A, wa[3*KY], wa[3*KY+1], wa[3*KY+2]) \
  C8(B, wb[3*KY], wb[3*KY+1], wb[3*KY+2])

template<bool IN_RELU, bool TRANS_W, bool OUT_RELU, bool HAS_BIAS>
__global__ __launch_bounds__(256) void k_conv3x3_v4(
    const float* __restrict__ in, const void* __restrict__ w,
    const void* __restrict__ bias, float* __restrict__ out,
    const int* __restrict__ flag, int Cin, int Cout)
{
  const int HW = 1024;
  const int PP = 33;
  const int PLANE = 32 * PP;
  __shared__ float sW[4608];
  __shared__ float sIn[2 * 1056];
  int fl = flag[0];
  int nq = Cout >> 2;
  int bid = blockIdx.x;
  int qc = bid % nq, n = bid / nq;
  int co0 = qc * 4;
  int tid = threadIdx.x;
  int tot = 4 * Cin * 9;
  for (int i = tid; i < tot; i += 256) {
    int cl = i / (Cin * 9), rem = i % (Cin * 9);
    int ci = rem / 9, k = rem % 9;
    int src = TRANS_W ? ((ci * Cout + co0 + cl) * 9 + (8 - k))
                      : (((co0 + cl) * Cin + ci) * 9 + k);
    sW[i] = ldg_in(w, src, fl);
  }
  int cp = tid >> 7;
  int tt = tid & 127;
  int ty = tt >> 2;
  int tx = tt & 3;
  int ox0 = tx * 8;
  int coA = co0 + cp * 2;
  const float* WA = sW + (cp * 2) * Cin * 9;
  const float* WB = WA + Cin * 9;
  float bvA = HAS_BIAS ? ldg_in(bias, coA, fl) : 0.f;
  float bvB = HAS_BIAS ? ldg_in(bias, coA + 1, fl) : 0.f;
  float A0=bvA,A1=bvA,A2=bvA,A3=bvA,A4=bvA,A5=bvA,A6=bvA,A7=bvA;
  float B0=bvB,B1=bvB,B2=bvB,B3=bvB,B4=bvB,B5=bvB,B6=bvB,B7=bvB;
  const float* ip = in + (size_t)n * Cin * HW;
  for (int cb = 0; cb < Cin; cb += 2) {
    __syncthreads();
    {
      const float4* g4 = (const float4*)(ip + cb * HW);
      #pragma unroll
      for (int j = 0; j < 2; ++j) {
        int i4 = tid + j * 256;
        float4 v = g4[i4];
        int flat = i4 * 4;
        int pl = flat >> 10, rem = flat & 1023;
        float* dst = sIn + pl * PLANE + (rem >> 5) * PP + (rem & 31);
        dst[0] = v.x; dst[1] = v.y; dst[2] = v.z; dst[3] = v.w;
      }
    }
    __syncthreads();
    #pragma unroll
    for (int u = 0; u < 2; ++u) {
      int ci = cb + u;
      const float* sP = sIn + u * PLANE;
      const float* wa = WA + ci * 9;
      const float* wb = WB + ci * 9;
      float x0, x1, x2, x3, x4, x5, x6, x7, x8, x9;
      if (ty > 0) {
        LOAD10(sP + (ty - 1) * PP)
        ROW8_AB(0)
      }
      {
        LOAD10(sP + ty * PP)
        ROW8_AB(1)
      }
      if (ty < 31) {
        LOAD10(sP + (ty + 1) * PP)
        ROW8_AB(2)
      }
    }
  }
  float* op = out + (size_t)(n * Cout + coA) * HW + ty * 32 + ox0;
  if (OUT_RELU) {
    op[0] = fmaxf(A0, 0.f); op[1] = fmaxf(A1, 0.f); op[2] = fmaxf(A2, 0.f); op[3] = fmaxf(A3, 0.f);
    op[4] = fmaxf(A4, 0.f); op[5] = fmaxf(A5, 0.f); op[6] = fmaxf(A6, 0.f); op[7] = fmaxf(A7, 0.f);
    op += HW;
    op[0] = fmaxf(B0, 0.f); op[1] = fmaxf(B1, 0.f); op[2] = fmaxf(B2, 0.f); op[3] = fmaxf(B3, 0.f);
    op[4] = fmaxf(B4, 0.f); op[5] = fmaxf(B5, 0.f); op[6] = fmaxf(B6, 0.f); op[7] = fmaxf(B7, 0.f);
  } else {
    op[0] = A0; op[1] = A1; op[2] = A2; op[3] = A3;
    op[4] = A4; op[5] = A5; op[6] = A6; op[7] = A7;
    op += HW;
    op[0] = B0; op[1] = B1; op[2] = B2; op[3] = B3;
    op[4] = B4; op[5] = B5; op[6] = B6; op[7] = B7;
  }
}

// ---------------- 1x1 conv @32x32: 4co x 4p register tile ----------------
template<bool ACCUM, bool HAS_BIAS, bool OUT_RELU>
__global__ __launch_bounds__(256) void k_conv1x1_t4(
    const float* __restrict__ in, const void* __restrict__ w,
    const void* __restrict__ bias, float* __restrict__ out,
    const int* __restrict__ flag, int Cin, int Cout)
{
  const int HW = 1024;
  __shared__ float sW[512];
  int fl = flag[0];
  int nq = Cout >> 2;
  int bid = blockIdx.x;
  int qc = bid % nq, n = bid / nq;
  int co0 = qc * 4;
  int tid = threadIdx.x;
  for (int i = tid; i < 4 * Cin; i += 256)
    sW[i] = ldg_in(w, co0 * Cin + i, fl);
  __syncthreads();
  float acc[4][4];
  #pragma unroll
  for (int c = 0; c < 4; ++c) {
    float bv = HAS_BIAS ? ldg_in(bias, co0 + c, fl) : 0.f;
    #pragma unroll
    for (int k = 0; k < 4; ++k) acc[c][k] = bv;
  }
  const float* ip = in + (size_t)n * Cin * HW + tid;
  for (int ci = 0; ci < Cin; ++ci) {
    const float* p = ip + ci * HW;
    float x0 = p[0], x1 = p[256], x2 = p[512], x3 = p[768];
    #pragma unroll
    for (int c = 0; c < 4; ++c) {
      float wv = sW[c * Cin + ci];
      acc[c][0] = fmaf(wv, x0, acc[c][0]);
      acc[c][1] = fmaf(wv, x1, acc[c][1]);
      acc[c][2] = fmaf(wv, x2, acc[c][2]);
      acc[c][3] = fmaf(wv, x3, acc[c][3]);
    }
  }
  #pragma unroll
  for (int c = 0; c < 4; ++c) {
    float* op = out + (size_t)(n * Cout + co0 + c) * HW + tid;
    #pragma unroll
    for (int k = 0; k < 4; ++k) {
      float v = acc[c][k];
      if (ACCUM) v += op[k * 256];
      if (OUT_RELU) v = fmaxf(v, 0.f);
      op[k * 256] = v;
    }
  }
}

// ---- ConvTranspose s2 k4 p1 parity-quad macros ----
#define LOADW16V(BASE) { \
  const float4* w4_ = (const float4*)(BASE); \
  float4 t0_ = w4_[0], t1_ = w4_[1], t2_ = w4_[2], t3_ = w4_[3]; \
  w00 = t0_.x; w01 = t0_.y; w02 = t0_.z; w03 = t0_.w; \
  w10 = t1_.x; w11 = t1_.y; w12 = t1_.z; w13 = t1_.w; \
  w20 = t2_.x; w21 = t2_.y; w22 = t2_.z; w23 = t2_.w; \
  w30 = t3_.x; w31 = t3_.y; w32 = t3_.z; w33 = t3_.w; }

#define CT_J(P00, P01, P10, P11, M0, M1, M2, C0, C1, C2, D0, D1, D2) \
  P00 = fmaf(w11, C1, fmaf(w13, C0, fmaf(w31, M1, fmaf(w33, M0, P00)))); \
  P01 = fmaf(w10, C2, fmaf(w12, C1, fmaf(w30, M2, fmaf(w32, M1, P01)))); \
  P10 = fmaf(w01, D1, fmaf(w03, D0, fmaf(w21, C1, fmaf(w23, C0, P10)))); \
  P11 = fmaf(w00, D2, fmaf(w02, D1, fmaf(w20, C2, fmaf(w22, C1, P11))));

#define DECL16(PX, BV) \
  float PX##A0=BV, PX##A1=BV, PX##A2=BV, PX##A3=BV, \
        PX##B0=BV, PX##B1=BV, PX##B2=BV, PX##B3=BV, \
        PX##C0=BV, PX##C1=BV, PX##C2=BV, PX##C3=BV, \
        PX##D0=BV, PX##D1=BV, PX##D2=BV, PX##D3=BV;

#define CT_CO(PX) \
  CT_J(PX##A0, PX##B0, PX##C0, PX##D0, m0, m1, m2, c0, c1, c2, d0, d1, d2) \
  CT_J(PX##A1, PX##B1, PX##C1, PX##D1, m1, m2, m3, c1, c2, c3, d1, d2, d3) \
  CT_J(PX##A2, PX##B2, PX##C2, PX##D2, m2, m3, m4, c2, c3, c4, d2, d3, d4) \
  CT_J(PX##A3, PX##B3, PX##C3, PX##D3, m3, m4, m5, c3, c4, c5, d3, d4, d5)

#define CT_STORE(PX, PTR, HO) \
  (PTR)[0] = fmaxf(PX##A0, 0.f); (PTR)[1] = fmaxf(PX##B0, 0.f); \
  (PTR)[2] = fmaxf(PX##A1, 0.f); (PTR)[3] = fmaxf(PX##B1, 0.f); \
  (PTR)[4] = fmaxf(PX##A2, 0.f); (PTR)[5] = fmaxf(PX##B2, 0.f); \
  (PTR)[6] = fmaxf(PX##A3, 0.f); (PTR)[7] = fmaxf(PX##B3, 0.f); \
  (PTR)[HO]     = fmaxf(PX##C0, 0.f); (PTR)[HO + 1] = fmaxf(PX##D0, 0.f); \
  (PTR)[HO + 2] = fmaxf(PX##C1, 0.f); (PTR)[HO + 3] = fmaxf(PX##D1, 0.f); \
  (PTR)[HO + 4] = fmaxf(PX##C2, 0.f); (PTR)[HO + 5] = fmaxf(PX##D2, 0.f); \
  (PTR)[HO + 6] = fmaxf(PX##C3, 0.f); (PTR)[HO + 7] = fmaxf(PX##D3, 0.f);

// ---------------- up1: convT s2 k4, 128ch 32x32 -> 64ch 64x64, 4 co/thread, staged input ----
__global__ __launch_bounds__(256) void k_convT_up1(
    const float* __restrict__ in, const void* __restrict__ w,
    const void* __restrict__ bias, float* __restrict__ out,
    const int* __restrict__ flag)
{
  const int Cin = 128, Cout = 64;
  const int PP = 33;
  __shared__ __align__(16) float sW[8192];
  __shared__ float sIn[32 * PP];
  int fl = flag[0];
  int bid = blockIdx.x;
  int cp = bid & 15, n = bid >> 4;
  int co0 = cp * 4;
  int tid = threadIdx.x;
  for (int i = tid; i < 8192; i += 256) {
    int cl = i >> 11, rem = i & 2047;
    int ci = rem >> 4, k = rem & 15;
    sW[i] = ldg_in(w, (ci * Cout + co0 + cl) * 16 + k, fl);
  }
  int qa = tid >> 3;
  int qb0 = (tid & 7) * 4;
  float bv0 = ldg_in(bias, co0, fl), bv1 = ldg_in(bias, co0 + 1, fl);
  float bv2 = ldg_in(bias, co0 + 2, fl), bv3 = ldg_in(bias, co0 + 3, fl);
  DECL16(u, bv0) DECL16(v, bv1) DECL16(y, bv2) DECL16(z, bv3)
  const float* ip = in + (size_t)n * Cin * 1024;
  bool vm = qa >= 1, vd = qa + 1 < 32;
  bool vl = qb0 > 0, vr = qb0 < 28;
  for (int ci = 0; ci < Cin; ++ci) {
    __syncthreads();
    {
      float4 g = ((const float4*)(ip + ci * 1024))[tid];
      float* dst = sIn + (tid >> 3) * PP + (tid & 7) * 4;
      dst[0] = g.x; dst[1] = g.y; dst[2] = g.z; dst[3] = g.w;
    }
    __syncthreads();
    const float* rm = sIn + (qa - 1) * PP;
    const float* rc = sIn + qa * PP;
    const float* rd = sIn + (qa + 1) * PP;
    float m0 = (vm && vl) ? rm[qb0 - 1] : 0.f;
    float m1 = vm ? rm[qb0] : 0.f, m2 = vm ? rm[qb0 + 1] : 0.f;
    float m3 = vm ? rm[qb0 + 2] : 0.f, m4 = vm ? rm[qb0 + 3] : 0.f;
    float m5 = (vm && vr) ? rm[qb0 + 4] : 0.f;
    float c0 = vl ? rc[qb0 - 1] : 0.f;
    float c1 = rc[qb0], c2 = rc[qb0 + 1], c3 = rc[qb0 + 2], c4 = rc[qb0 + 3];
    float c5 = vr ? rc[qb0 + 4] : 0.f;
    float d0 = (vd && vl) ? rd[qb0 - 1] : 0.f;
    float d1 = vd ? rd[qb0] : 0.f, d2 = vd ? rd[qb0 + 1] : 0.f;
    float d3 = vd ? rd[qb0 + 2] : 0.f, d4 = vd ? rd[qb0 + 3] : 0.f;
    float d5 = (vd && vr) ? rd[qb0 + 4] : 0.f;
    float w00, w01, w02, w03, w10, w11, w12, w13, w20, w21, w22, w23, w30, w31, w32, w33;
    { LOADW16V(sW + ci * 16)        CT_CO(u) }
    { LOADW16V(sW + 2048 + ci * 16) CT_CO(v) }
    { LOADW16V(sW + 4096 + ci * 16) CT_CO(y) }
    { LOADW16V(sW + 6144 + ci * 16) CT_CO(z) }
  }
  float* op = out + ((size_t)(n * Cout + co0) * 64 + 2 * qa) * 64 + 2 * qb0;
  CT_STORE(u, op, 64) op += (size_t)64 * 64;
  CT_STORE(v, op, 64) op += (size_t)64 * 64;
  CT_STORE(y, op, 64) op += (size_t)64 * 64;
  CT_STORE(z, op, 64)
}

// ---------------- up2: convT s2 k4, 64ch 64x64 -> 3ch 128x128, all 3 co/thread ----------------
__global__ __launch_bounds__(256) void k_convT_up2(
    const float* __restrict__ in, const void* __restrict__ w,
    const void* __restrict__ bias, float* __restrict__ out,
    const int* __restrict__ flag)
{
  const int Cin = 64;
  __shared__ __align__(16) float sW[3072];
  int fl = flag[0];
  int bid = blockIdx.x;
  int s = bid & 7, n = bid >> 3;
  int tid = threadIdx.x;
  for (int i = tid; i < 3072; i += 256)
    sW[i] = ldg_in(w, i, fl);
  __syncthreads();
  int qa = s * 8 + (tid >> 5);
  int qb0 = (tid & 31) * 2;
  float bp = ldg_in(bias, 0, fl), bq = ldg_in(bias, 1, fl), br = ldg_in(bias, 2, fl);
  float pA0 = bp, pA1 = bp, pB0 = bp, pB1 = bp, pC0 = bp, pC1 = bp, pD0 = bp, pD1 = bp;
  float qA0 = bq, qA1 = bq, qB0_ = bq, qB1 = bq, qC0 = bq, qC1 = bq, qD0 = bq, qD1 = bq;
  float rA0 = br, rA1 = br, rB0 = br, rB1 = br, rC0 = br, rC1 = br, rD0 = br, rD1 = br;
  const float* ip = in + (size_t)n * Cin * 4096;
  bool vm = qa >= 1, vd = qa + 1 < 64;
  bool vl = qb0 > 0, vr = qb0 < 62;
  for (int ci = 0; ci < Cin; ++ci) {
    const float* p = ip + ci * 4096;
    const float* rm = p + (qa - 1) * 64;
    const float* rc = p + qa * 64;
    const float* rd = p + (qa + 1) * 64;
    float m0 = (vm && vl) ? rm[qb0 - 1] : 0.f;
    float m1 = vm ? rm[qb0] : 0.f, m2 = vm ? rm[qb0 + 1] : 0.f;
    float m3 = (vm && vr) ? rm[qb0 + 2] : 0.f;
    float c0 = vl ? rc[qb0 - 1] : 0.f;
    float c1 = rc[qb0], c2 = rc[qb0 + 1];
    float c3 = vr ? rc[qb0 + 2] : 0.f;
    float d0 = (vd && vl) ? rd[qb0 - 1] : 0.f;
    float d1 = vd ? rd[qb0] : 0.f, d2 = vd ? rd[qb0 + 1] : 0.f;
    float d3 = (vd && vr) ? rd[qb0 + 2] : 0.f;
    float w00, w01, w02, w03, w10, w11, w12, w13, w20, w21, w22, w23, w30, w31, w32, w33;
    {
      LOADW16V(sW + ci * 48)
      CT_J(pA0, pB0, pC0, pD0, m0, m1, m2, c0, c1, c2, d0, d1, d2)
      CT_J(pA1, pB1, pC1, pD1, m1, m2, m3, c1, c2, c3, d1, d2, d3)
    }
    {
      LOADW16V(sW + ci * 48 + 16)
      CT_J(qA0, qB0_, qC0, qD0, m0, m1, m2, c0, c1, c2, d0, d1, d2)
      CT_J(qA1, qB1, qC1, qD1, m1, m2, m3, c1, c2, c3, d1, d2, d3)
    }
    {
      LOADW16V(sW + ci * 48 + 32)
      CT_J(rA0, rB0, rC0, rD0, m0, m1, m2, c0, c1, c2, d0, d1, d2)
      CT_J(rA1, rB1, rC1, rD1, m1, m2, m3, c1, c2, c3, d1, d2, d3)
    }
  }
  float* op = out + ((size_t)(n * 3 + 0) * 128 + 2 * qa) * 128 + 2 * qb0;
  op[0] = pA0; op[1] = pB0; op[2] = pA1; op[3] = pB1;
  op[128] = pC0; op[129] = pD0; op[130] = pC1; op[131] = pD1;
  op += (size_t)128 * 128;
  op[0] = qA0; op[1] = qB0_; op[2] = qA1; op[3] = qB1;
  op[128] = qC0; op[129] = qD0; op[130] = qC1; op[131] = qD1;
  op += (size_t)128 * 128;
  op[0] = rA0; op[1] = rB0; op[2] = rA1; op[3] = rB1;
  op[128] = rC0; op[129] = rD0; op[130] = rC1; op[131] = rD1;
}

// ---------------- VQ phase 1: per-chunk argmin; float4 LDS reads (broadcast) ----------------
// PE=68 (16B-aligned rows). Chain order per k identical to scalar version
// (d ascending) -> bit-identical distances -> exact first-min idx.
__global__ __launch_bounds__(256) void k_vq1(
    const float* __restrict__ z, const void* __restrict__ emb,
    const int* __restrict__ flag, float* __restrict__ distb, float* __restrict__ idxb)
{
  const int PE = 68;
  __shared__ __align__(16) float sE[128 * PE];
  __shared__ float sEE[128];
  int fl = flag[0];
  int tid = threadIdx.x;
  int bid = blockIdx.x;
  int ch = bid & 3, vb = bid >> 2;
  int n = vb * 256 + tid;
  int nb = n >> 10, p = n & 1023;
  const float* zp = z + nb * 65536 + p;
  float zv[64];
  float zz = 0.f;
  #pragma unroll
  for (int d = 0; d < 64; ++d) { zv[d] = zp[d * 1024]; zz = fmaf(zv[d], zv[d], zz); }
  float best = 3.4e38f; int bidx = ch * 256;
  for (int kb = ch * 2; kb < ch * 2 + 2; ++kb) {
    __syncthreads();
    for (int i = tid; i < 8192; i += 256)
      sE[(i >> 6) * PE + (i & 63)] = ldg_in(emb, kb * 8192 + i, fl);
    __syncthreads();
    if (tid < 128) {
      const float4* ep4 = (const float4*)(sE + tid * PE);
      float s = 0.f;
      #pragma unroll
      for (int i = 0; i < 16; ++i) {
        float4 v = ep4[i];
        s = fmaf(v.x, v.x, s); s = fmaf(v.y, v.y, s);
        s = fmaf(v.z, v.z, s); s = fmaf(v.w, v.w, s);
      }
      sEE[tid] = s;
    }
    __syncthreads();
    #pragma unroll 2
    for (int k = 0; k < 128; ++k) {
      const float4* ep4 = (const float4*)(sE + k * PE);
      float dot = 0.f;
      #pragma unroll
      for (int i = 0; i < 16; ++i) {
        float4 v = ep4[i];               // wave-uniform addr -> LDS broadcast
        dot = fmaf(zv[4*i],     v.x, dot);
        dot = fmaf(zv[4*i + 1], v.y, dot);
        dot = fmaf(zv[4*i + 2], v.z, dot);
        dot = fmaf(zv[4*i + 3], v.w, dot);
      }
      float dist = zz + sEE[k] - 2.f * dot;
      if (dist < best) { best = dist; bidx = kb * 128 + k; }  // strict <: first min wins
    }
  }
  distb[ch * 65536 + n] = best;
  idxb[ch * 65536 + n] = (float)bidx;
}

// ---------------- VQ phase 2: combine chunks, gather zq, loss partials ----------------
__global__ __launch_bounds__(256) void k_vq2(
    const float* __restrict__ z, const void* __restrict__ emb,
    const int* __restrict__ flag, const float* __restrict__ distb,
    const float* __restrict__ idxb, float* __restrict__ zq,
    float* __restrict__ idx_out, float* __restrict__ lossp, int lossbase)
{
  __shared__ float wsum[4];
  int fl = flag[0];
  int tid = threadIdx.x;
  int n = blockIdx.x * 256 + tid;
  float best = distb[n];
  int bidx = (int)idxb[n];
  #pragma unroll
  for (int c = 1; c < 4; ++c) {
    float d = distb[c * 65536 + n];
    if (d < best) { best = d; bidx = (int)idxb[c * 65536 + n]; }  // earlier chunk wins ties
  }
  idx_out[n] = (float)bidx;
  int nb = n >> 10, p = n & 1023;
  const float* zp = z + nb * 65536 + p;
  float* qp = zq + nb * 65536 + p;
  float ls = 0.f;
  #pragma unroll
  for (int d = 0; d < 64; ++d) {
    float e = ldg_in(emb, bidx * 64 + d, fl);
    float zvd = zp[d * 1024];
    qp[d * 1024] = e;
    float df = e - zvd;
    ls = fmaf(df, df, ls);
  }
  #pragma unroll
  for (int off = 32; off > 0; off >>= 1) ls += __shfl_down(ls, off);
  if ((tid & 63) == 0) wsum[tid >> 6] = ls;
  __syncthreads();
  if (tid == 0) lossp[lossbase + blockIdx.x] = wsum[0] + wsum[1] + wsum[2] + wsum[3];
}

__global__ void k_loss_final(const float* __restrict__ lossp, float* __restrict__ out) {
  if (threadIdx.x == 0 && blockIdx.x == 0) {
    float s = 0.f;
    for (int i = 0; i < 256; ++i) s += lossp[i];
    float L = s * (1.f / 4194304.f);
    out[R_RECON + 0] = L;
    out[R_RECON + 1] = L;
  }
}

extern "C" void kernel_launch(void* const* d_in, const int* in_sizes, int n_in,
                              void* d_out, int out_size, void* d_ws, size_t ws_size,
                              hipStream_t stream)
{
  float* out = (float*)d_out;          // fp32 output (established R8-R10)

  float* F = (float*)d_ws;
  float* LOSSP = F;
  int* FLAG = (int*)(F + 256);
  float* VQD = F + 272;
  float* VQI = VQD + 262144;
  float* A = VQI + 262144;

  int Bc = 64;
  while (Bc > 1 && 4ull * (272ull + 524288ull + (size_t)Bc * 393216ull) > ws_size) Bc >>= 1;
  float* H1 = A;
  float* H2 = A + (size_t)Bc * 262144;
  float* H3 = A;
  float* T  = A + (size_t)Bc * 131072;
  float* Z  = A + (size_t)Bc * 163840;
  float* D1 = H2;
  float* D2 = A;

  const void* patch = d_in[0];
  const void* ew1 = d_in[1];  const void* eb1 = d_in[2];
  const void* ew2 = d_in[3];  const void* eb2 = d_in[4];
  const void* ew3 = d_in[5];  const void* eb3 = d_in[6];
  const void* er1a = d_in[7]; const void* er1b = d_in[8];
  const void* er2a = d_in[9]; const void* er2b = d_in[10];
  const void* pqw = d_in[11]; const void* pqb = d_in[12];
  const void* emb = d_in[13];
  const void* dw1 = d_in[14]; const void* db1 = d_in[15];
  const void* dr1a = d_in[16]; const void* dr1b = d_in[17];
  const void* dr2a = d_in[18]; const void* dr2b = d_in[19];
  const void* dw2 = d_in[20]; const void* db2 = d_in[21];
  const void* dw3 = d_in[22]; const void* db3 = d_in[23];

  k_detect<<<1, 256, 0, stream>>>((const u16*)patch, FLAG);

  int NC = 64 / Bc;
  for (int c = 0; c < NC; ++c) {
    int b0 = c * Bc;

    // ---- encoder ----
    k_enc1<<<Bc * 128, 256, 0, stream>>>(patch, ew1, eb1, H1, FLAG, b0);
    k_enc2<<<Bc * 16, 256, 0, stream>>>(H1, ew2, eb2, H2, FLAG);
    k_conv3x3_v4<false, false, false, true><<<Bc * 32, 256, 0, stream>>>(H2, ew3, eb3, H3, FLAG, 128, 128);
    k_conv3x3_v4<true, false, true, false><<<Bc * 8, 256, 0, stream>>>(H3, er1a, nullptr, T, FLAG, 128, 32);
    k_conv1x1_t4<true, false, false><<<Bc * 32, 256, 0, stream>>>(T, er1b, nullptr, H3, FLAG, 32, 128);
    k_conv3x3_v4<true, false, true, false><<<Bc * 8, 256, 0, stream>>>(H3, er2a, nullptr, T, FLAG, 128, 32);
    k_conv1x1_t4<true, false, true><<<Bc * 32, 256, 0, stream>>>(T, er2b, nullptr, H3, FLAG, 32, 128);
    k_conv1x1_t4<false, true, false><<<Bc * 16, 256, 0, stream>>>(H3, pqw, pqb, Z, FLAG, 128, 64);

    // ---- VQ ----
    k_vq1<<<Bc * 16, 256, 0, stream>>>(Z, emb, FLAG, VQD, VQI);
    k_vq2<<<Bc * 4, 256, 0, stream>>>(Z, emb, FLAG, VQD, VQI, Z,
                                      out + R_RECON + 2 + (size_t)b0 * 1024, LOSSP, b0 * 4);

    // ---- decoder ----
    k_conv3x3_v4<false, true, false, true><<<Bc * 32, 256, 0, stream>>>(Z, dw1, db1, D1, FLAG, 64, 128);
    k_conv3x3_v4<true, false, true, false><<<Bc * 8, 256, 0, stream>>>(D1, dr1a, nullptr, T, FLAG, 128, 32);
    k_conv1x1_t4<true, false, false><<<Bc * 32, 256, 0, stream>>>(T, dr1b, nullptr, D1, FLAG, 32, 128);
    k_conv3x3_v4<true, false, true, false><<<Bc * 8, 256, 0, stream>>>(D1, dr2a, nullptr, T, FLAG, 128, 32);
    k_conv1x1_t4<true, false, true><<<Bc * 32, 256, 0, stream>>>(T, dr2b, nullptr, D1, FLAG, 32, 128);
    k_convT_up1<<<Bc * 16, 256, 0, stream>>>(D1, dw2, db2, D2, FLAG);
    k_convT_up2<<<Bc * 8, 256, 0, stream>>>(D2, dw3, db3, out + (size_t)b0 * 49152, FLAG);
  }

  k_loss_final<<<1, 64, 0, stream>>>(LOSSP, out);
}